// Round 20
// baseline (244.866 us; speedup 1.0000x reference)
//
#include <hip/hip_runtime.h>
#include <cstdint>

#define DEV __device__ __forceinline__

using short8 = __attribute__((ext_vector_type(8))) short;
using f32x4  = __attribute__((ext_vector_type(4))) float;

#define MFMA __builtin_amdgcn_mfma_f32_16x16x32_bf16

DEV float bf2f(unsigned short u){
  union { unsigned int i; float f; } v; v.i = ((unsigned int)u) << 16; return v.f;
}
DEV unsigned short f2bf(float f){
  union { float f; unsigned int i; } v; v.f = f;
  unsigned int x = v.i;
  return (unsigned short)((x + 0x7fffu + ((x >> 16) & 1u)) >> 16);
}
DEV unsigned int cvtpk(float a, float b){
  unsigned int r;
  asm("v_cvt_pk_bf16_f32 %0, %1, %2" : "=v"(r) : "v"(a), "v"(b));
  return r;
}

// ---------------- prep: transposed bf16 weights ----------------
__global__ __launch_bounds__(256) void k_prep(const float* __restrict__ w_qkv,
                                              const float* __restrict__ w_out,
                                              unsigned short* __restrict__ wqh_t,
                                              unsigned short* __restrict__ woh_t,
                                              unsigned short* __restrict__ wol_t){
  int i = blockIdx.x*256 + threadIdx.x;
  if (i < 196608){
    int o = i >> 8, c = i & 255, kc = c >> 5, kk = c & 31;
    wqh_t[kc*24576 + o*32 + kk] = f2bf(w_qkv[i]);
  } else {
    int j = i - 196608;
    if (j < 65536){
      int o = j >> 8, c = j & 255, kc = c >> 5, kk = c & 31;
      float v = w_out[j];
      unsigned short h = f2bf(v);
      int dst = kc*8192 + o*32 + kk;
      woh_t[dst] = h;
      wol_t[dst] = f2bf(v - bf2f(h));
    }
  }
}

// ---------------- region means of x (fp32 exact, coalesced; 4x z-split) ----------------
__global__ __launch_bounds__(256) void k_xbar(const float* __restrict__ x,
                                              float* __restrict__ xbar){
  const int ry = blockIdx.x, n = blockIdx.y, cz = blockIdx.z;
  const int t = threadIdx.x, cg = t>>6, lane = t&63;
  for (int ci = 0; ci < 16; ++ci){
    int c = cz*64 + ci*4 + cg;
    const float* base = x + ((size_t)n*256 + c)*3136 + ry*8*56;
    float acc = 0.f;
    if (lane < 56){
      #pragma unroll
      for (int yy = 0; yy < 8; ++yy) acc += base[yy*56 + lane];
    }
    acc += __shfl_xor(acc, 1, 64);
    acc += __shfl_xor(acc, 2, 64);
    acc += __shfl_xor(acc, 4, 64);
    if ((lane&7) == 0 && lane < 56)
      xbar[((size_t)n*49 + ry*7 + (lane>>3))*256 + c] = acc * (1.0f/64.0f);
  }
}

// ---------------- q_r / k_r = W_{q,k} * xbar + b (fp32; 7-region chunks) ----------------
__global__ __launch_bounds__(256) void k_qrkr(const float* __restrict__ xbar,
                                              const float* __restrict__ w_qkv,
                                              const float* __restrict__ b_qkv,
                                              float* __restrict__ q_r,
                                              float* __restrict__ k_r){
  __shared__ float4 xb4[448];
  const int wb = blockIdx.x, n = blockIdx.y, rz = blockIdx.z, t = threadIdx.x;
  {
    const float4* src = (const float4*)(xbar + (size_t)n*12544) + rz*448;
    for (int i = t; i < 448; i += 256) xb4[i] = src[i];
  }
  const int wrow = wb*64 + (t>>2), kl = t&3;
  float4 wreg[16];
  {
    const float4* wsrc = (const float4*)(w_qkv + (size_t)wrow*256) + kl*16;
    #pragma unroll
    for (int i = 0; i < 16; ++i) wreg[i] = wsrc[i];
  }
  __syncthreads();
  const float bias = b_qkv[wrow];
  for (int rl = 0; rl < 7; ++rl){
    float s = 0.f;
    #pragma unroll
    for (int i = 0; i < 16; ++i){
      float4 a = wreg[i], b = xb4[rl*64 + kl*16 + i];
      s += a.x*b.x + a.y*b.y + a.z*b.z + a.w*b.w;
    }
    s += __shfl_xor(s, 1, 64);
    s += __shfl_xor(s, 2, 64);
    if (kl == 0){
      int reg = rz*7 + rl;
      if (wrow < 256) q_r[((size_t)n*49 + reg)*256 + wrow] = s + bias;
      else            k_r[((size_t)n*49 + reg)*256 + wrow - 256] = s + bias;
    }
  }
}

// ---------------- routing scores + top-4 (ties: lowest index first) ----------------
__global__ __launch_bounds__(64) void k_topk(const float* __restrict__ q_r,
                                             const float* __restrict__ k_r,
                                             int* __restrict__ idx){
  __shared__ float sc[49];
  const int qreg = blockIdx.x, n = blockIdx.y, l = threadIdx.x;
  const float* qrow = q_r + ((size_t)n*49 + qreg)*256;
  const float q0 = qrow[l], q1 = qrow[l+64], q2 = qrow[l+128], q3 = qrow[l+192];
  for (int kr = 0; kr < 49; ++kr){
    const float* krow = k_r + ((size_t)n*49 + kr)*256;
    float s = q0*krow[l] + q1*krow[l+64] + q2*krow[l+128] + q3*krow[l+192];
    #pragma unroll
    for (int m = 1; m < 64; m <<= 1) s += __shfl_xor(s, m, 64);
    if (l == 0) sc[kr] = s;
  }
  __syncthreads();
  if (l == 0){
    #pragma unroll
    for (int s = 0; s < 4; ++s){
      float best = -3.4e38f; int bi = 0;
      for (int kr = 0; kr < 49; ++kr) if (sc[kr] > best){ best = sc[kr]; bi = kr; }
      idx[((size_t)n*49 + qreg)*4 + s] = bi;
      sc[bi] = -3.4e38f;
    }
  }
}

// ---------------- qkv 1x1 conv GEMM: o-split across blocks, XCD-co-located ----------------
__global__ __launch_bounds__(256) void k_qkv(const float* __restrict__ x,
                                             const unsigned short* __restrict__ wqh_t,
                                             const float* __restrict__ b_qkv,
                                             unsigned short* __restrict__ q_rm,
                                             unsigned short* __restrict__ k_rm,
                                             unsigned short* __restrict__ v_t){
  __shared__ unsigned short xl[64*256]; // [tok][c], ushort idx ^= (tok&15)<<3
  const int lin = blockIdx.x;
  const int xcd = lin & 7, jj = lin >> 3;
  const int jobid = xcd*294 + jj;
  const int z = jobid % 3;
  const int pair = jobid / 3;
  const int reg = pair % 49, n = pair / 49;

  const int ry = reg/7, rx = reg%7;
  const int t = threadIdx.x, w = t>>6, g = (t>>4)&3, c16 = t&15;
  {
    const int pq = (t & 15)*4, cc = t >> 4;
    const int row = pq >> 3, col = pq & 7;
    const float* src = x + ((size_t)n*256 + cc)*3136 + (ry*8 + row)*56 + rx*8 + col;
    for (int ci = 0; ci < 16; ++ci){
      float4 v4 = *reinterpret_cast<const float4*>(src + (size_t)ci*16*3136);
      int c = ci*16 + cc;
      xl[((pq+0)*256 + c) ^ (((pq+0)&15)<<3)] = f2bf(v4.x);
      xl[((pq+1)*256 + c) ^ (((pq+1)&15)<<3)] = f2bf(v4.y);
      xl[((pq+2)*256 + c) ^ (((pq+2)&15)<<3)] = f2bf(v4.z);
      xl[((pq+3)*256 + c) ^ (((pq+3)&15)<<3)] = f2bf(v4.w);
    }
  }
  __syncthreads();
  const size_t rb = (size_t)(n*8)*49 + reg;
  const int osw = w*16;

  if (z < 2){
    f32x4 acc[4][4] = {};
    for (int kc = 0; kc < 8; ++kc){
      short8 xf[4];
      #pragma unroll
      for (int pt = 0; pt < 4; ++pt){
        int p = pt*16 + c16;
        xf[pt] = *reinterpret_cast<const short8*>(&xl[(p*256 + kc*32 + 8*g) ^ ((p&15)<<3)]);
      }
      #pragma unroll
      for (int oi = 0; oi < 4; ++oi){
        const int os = z*256 + oi*64 + osw;
        short8 wf = *reinterpret_cast<const short8*>(wqh_t + (size_t)kc*24576 + (os + c16)*32 + 8*g);
        #pragma unroll
        for (int pt = 0; pt < 4; ++pt)
          acc[oi][pt] = MFMA(xf[pt], wf, acc[oi][pt], 0, 0, 0);
      }
    }
    #pragma unroll
    for (int oi = 0; oi < 4; ++oi){
      const int o = z*256 + oi*64 + osw + c16;
      const float bias = b_qkv[o];
      const int oc = o & 255, hh = oc >> 5, dd = oc & 31;
      unsigned short* dst = ((z == 0) ? q_rm : k_rm) + (rb + hh*49)*2048 + dd;
      #pragma unroll
      for (int pt = 0; pt < 4; ++pt)
        #pragma unroll
        for (int r = 0; r < 4; ++r){
          int tok = pt*16 + 4*g + r;
          dst[tok*32] = f2bf(acc[oi][pt][r] + bias);
        }
    }
  } else {
    f32x4 acc[4][4] = {};
    for (int kc = 0; kc < 8; ++kc){
      short8 xf[4];
      #pragma unroll
      for (int pt = 0; pt < 4; ++pt){
        int p = pt*16 + c16;
        xf[pt] = *reinterpret_cast<const short8*>(&xl[(p*256 + kc*32 + 8*g) ^ ((p&15)<<3)]);
      }
      #pragma unroll
      for (int oi = 0; oi < 4; ++oi){
        const int os = oi*64 + osw;
        short8 wf = *reinterpret_cast<const short8*>(wqh_t + (size_t)kc*24576 + (512 + os + c16)*32 + 8*g);
        #pragma unroll
        for (int pt = 0; pt < 4; ++pt)
          acc[oi][pt] = MFMA(wf, xf[pt], acc[oi][pt], 0, 0, 0);
      }
    }
    #pragma unroll
    for (int oi = 0; oi < 4; ++oi){
      #pragma unroll
      for (int r = 0; r < 4; ++r){
        int c = oi*64 + osw + 4*g + r;
        const float bias = b_qkv[512 + c];
        int hh = c >> 5, ch = c & 31;
        unsigned short* dst = v_t + (rb + hh*49)*2048 + ch*32;
        #pragma unroll
        for (int pt = 0; pt < 4; ++pt){
          int tok = pt*16 + c16;
          dst[(tok>>5)*1024 + (tok&31)] = f2bf(acc[oi][pt][r] + bias);
        }
      }
    }
  }
}

// ---------------- attention + fused LEPE per (n, head, region) ----------------
// Two-half ONLINE softmax (s regs 64->32) with PER-QUERY oacc rescale:
// resc is owned by softmax-lane q=c16; oacc rows are queries 4g+r, so the
// rescale is broadcast via shfl(resc, 4g+r) before applying (R18 bugfix).
__global__ __launch_bounds__(256, 4) void k_attn(const unsigned short* __restrict__ q_rm,
                                                 const unsigned short* __restrict__ k_rm,
                                                 const unsigned short* __restrict__ v_t,
                                                 const int* __restrict__ idx,
                                                 const float* __restrict__ w_lepe,
                                                 const float* __restrict__ b_lepe,
                                                 unsigned short* __restrict__ att_hi,
                                                 unsigned short* __restrict__ att_lo){
  __shared__ unsigned short halo[10*320];   // [dy][c][10] (x+1), bank-step 5 over c
  __shared__ float wl_s[288];
  __shared__ float bl_s[32];

  // XCD-aware remap
  const int lin = blockIdx.x + 49*(blockIdx.y + 8*blockIdx.z);
  const int xcd = lin & 7, j = lin >> 3;
  const int jq = j / 49;
  const int qreg = j - jq*49;
  const int hn = jq*8 + xcd;
  const int h = hn & 7, n = hn >> 3;

  const int t = threadIdx.x, w = t>>6, g = (t>>4)&3, c16 = t&15;
  const int ry = qreg/7, rx = qreg%7;
  const int gy0 = ry*8;

  int4 ridx = *reinterpret_cast<const int4*>(idx + ((size_t)n*49 + qreg)*4);
  int regs[4] = {ridx.x, ridx.y, ridx.z, ridx.w};

  const size_t hb = ((size_t)(n*8 + h))*49;

  // ---- stage LEPE weights + materialized halo rows ----
  wl_s[t < 288 ? t : 0] = w_lepe[h*288 + (t < 288 ? t : 0)];
  if (t < 32){
    wl_s[256 + t] = w_lepe[h*288 + 256 + t];
    bl_s[t] = b_lepe[h*32 + t];
  }
  #pragma unroll
  for (int pass = 0; pass < 2; ++pass){
    int s = pass ? (256 + t) : t;
    if (pass == 0 || t < 64){
      const int dy = s >> 5, c = s & 31;
      const int yy = gy0 + dy - 1;
      short8 inner = {0,0,0,0,0,0,0,0};
      unsigned short eL = 0, eR = 0;
      if (yy >= 0 && yy < 56){
        const int iry = yy >> 3, y7 = yy & 7;
        const size_t rowb = (size_t)(y7>>2)*1024 + c*32 + (y7&3)*8;
        inner = *reinterpret_cast<const short8*>(v_t + (hb + iry*7 + rx)*2048 + rowb);
        if (rx > 0) eL = v_t[(hb + iry*7 + rx - 1)*2048 + rowb + 7];
        if (rx < 6) eR = v_t[(hb + iry*7 + rx + 1)*2048 + rowb];
      }
      unsigned short* drow = &halo[dy*320 + c*10];
      drow[0] = eL;
      #pragma unroll
      for (int jj2 = 0; jj2 < 8; ++jj2) drow[1 + jj2] = (unsigned short)inner[jj2];
      drow[9] = eR;
    }
  }

  // ---- Q frag (B operand) ----
  const int qtok = w*16 + c16;
  short8 qf = *reinterpret_cast<const short8*>(q_rm + (hb + qreg)*2048 + qtok*32 + 8*g);

  const float scale2 = 0.1767766952966369f * 1.4426950408889634f; // d^-.5 * log2(e)
  const int srcA = (t & 15) | ((t & 16) << 1);   // 32*(g&1) + c16
  const int srcB = srcA + 16;
  const bool gsel = (t & 32) != 0;               // g>>1

  float m_run = -3.4e38f, su = 0.f;
  f32x4 oacc[2] = {};

  #pragma unroll
  for (int h2 = 0; h2 < 2; ++h2){
    // ---- QK^T for this half (regions regs[2*h2], regs[2*h2+1]) ----
    f32x4 s[8];
    #pragma unroll
    for (int f = 0; f < 8; ++f){
      const int tt = (f&3)*16 + c16;
      short8 kf = *reinterpret_cast<const short8*>(
          k_rm + (hb + regs[h2*2 + (f>>2)])*2048 + tt*32 + 8*g);
      f32x4 z = {0.f, 0.f, 0.f, 0.f};
      s[f] = MFMA(kf, qf, z, 0, 0, 0);
    }

    // ---- local max across this half's 32 in-lane values + g-lanes ----
    float ml = -3.4e38f;
    #pragma unroll
    for (int f = 0; f < 8; ++f)
      #pragma unroll
      for (int r = 0; r < 4; ++r) ml = fmaxf(ml, s[f][r]);
    ml = fmaxf(ml, __shfl_xor(ml, 16, 64));
    ml = fmaxf(ml, __shfl_xor(ml, 32, 64));

    // ---- online rescale of running state (per-query for oacc!) ----
    const float mnew = (h2 == 0) ? ml : fmaxf(m_run, ml);
    if (h2 != 0){
      const float resc = exp2f((m_run - mnew) * scale2);  // for query q=c16
      su *= resc;
      float rq[4];
      #pragma unroll
      for (int r = 0; r < 4; ++r)
        rq[r] = __shfl(resc, 4*g + r, 64);                 // query tok=4g+r
      #pragma unroll
      for (int dt = 0; dt < 2; ++dt)
        #pragma unroll
        for (int r = 0; r < 4; ++r)
          oacc[dt][r] *= rq[r];
    }
    m_run = mnew;

    // ---- exp ----
    const float nms = -mnew * scale2;
    #pragma unroll
    for (int f = 0; f < 8; ++f)
      #pragma unroll
      for (int r = 0; r < 4; ++r){
        float e = exp2f(fmaf(s[f][r], scale2, nms));
        s[f][r] = e; su += e;
      }

    // ---- PV for this half: A-frag assembled via bpermute exchange ----
    #pragma unroll
    for (int tcl = 0; tcl < 4; ++tcl){
      const int fb = (tcl>>1)*4 + (tcl&1)*2;
      unsigned int a0 = cvtpk(s[fb][0],   s[fb][1]);
      unsigned int a1 = cvtpk(s[fb][2],   s[fb][3]);
      unsigned int b0 = cvtpk(s[fb+1][0], s[fb+1][1]);
      unsigned int b1 = cvtpk(s[fb+1][2], s[fb+1][3]);
      unsigned int wa0 = __shfl((int)a0, srcA, 64), wa1 = __shfl((int)a1, srcA, 64);
      unsigned int wa2 = __shfl((int)a0, srcB, 64), wa3 = __shfl((int)a1, srcB, 64);
      unsigned int wb0 = __shfl((int)b0, srcA, 64), wb1 = __shfl((int)b1, srcA, 64);
      unsigned int wb2 = __shfl((int)b0, srcB, 64), wb3 = __shfl((int)b1, srcB, 64);
      union { unsigned int u[4]; short8 s8; } pfu;
      pfu.u[0] = gsel ? wb0 : wa0;
      pfu.u[1] = gsel ? wb1 : wa1;
      pfu.u[2] = gsel ? wb2 : wa2;
      pfu.u[3] = gsel ? wb3 : wa3;
      const size_t vb = (hb + regs[h2*2 + (tcl>>1)])*2048 + (tcl&1)*1024 + 8*g;
      #pragma unroll
      for (int dt = 0; dt < 2; ++dt){
        short8 vf = *reinterpret_cast<const short8*>(v_t + vb + (dt*16 + c16)*32);
        oacc[dt] = MFMA(pfu.s8, vf, oacc[dt], 0, 0, 0);
      }
    }
  }

  // ---- final sum reduce + inv ----
  su += __shfl_xor(su, 16, 64);
  su += __shfl_xor(su, 32, 64);
  const float inv_lane = __builtin_amdgcn_rcpf(su);
  float invq[4];
  #pragma unroll
  for (int r = 0; r < 4; ++r)
    invq[r] = __shfl(inv_lane, 4*g + r, 64);

  // ---- barrier: halo ready; LEPE epilogue = pure LDS loads + FMA ----
  __syncthreads();
  const int tok0 = w*16 + 4*g;
  const int ty = tok0>>3, tx0 = tok0&7;     // tx0 in {0,4}
  #pragma unroll
  for (int dt = 0; dt < 2; ++dt){
    const int cl = dt*16 + c16;
    float wl[9];
    #pragma unroll
    for (int kk = 0; kk < 9; ++kk) wl[kk] = wl_s[cl*9 + kk];
    const float bl = bl_s[cl];
    float vwin[3][6];
    #pragma unroll
    for (int dy = 0; dy < 3; ++dy){
      const unsigned short* hrow = &halo[(ty+dy)*320 + cl*10 + tx0];
      #pragma unroll
      for (int jj = 0; jj < 6; ++jj)
        vwin[dy][jj] = bf2f(hrow[jj]);
    }
    #pragma unroll
    for (int r = 0; r < 4; ++r){
      float a = fmaf(oacc[dt][r], invq[r], bl);
      #pragma unroll
      for (int dy = 0; dy < 3; ++dy)
        #pragma unroll
        for (int dx = 0; dx < 3; ++dx)
          a += wl[dy*3 + dx] * vwin[dy][r + dx];
      int tok = tok0 + r;
      size_t o = ((size_t)(n*49 + qreg)*8 + h)*2048 + tok*32 + dt*16 + c16;
      unsigned short hi = (unsigned short)cvtpk(a, a);
      att_hi[o] = hi;
      float alo = a - bf2f(hi);
      att_lo[o] = (unsigned short)cvtpk(alo, alo);
    }
  }
}

// ---------------- output projection (R14 exact: bf16x3; ah/al 16B loads; XCD write-merge) ----------------
__global__ __launch_bounds__(512) void k_oproj(const unsigned short* __restrict__ ah_,
                                               const unsigned short* __restrict__ al_,
                                               const unsigned short* __restrict__ wh_t,
                                               const unsigned short* __restrict__ wl_t,
                                               const float* __restrict__ b_out,
                                               float* __restrict__ out){
  // grid (784); jobid = xcd*98 + (lin>>3): each XCD owns 2 complete images
  const int lin = blockIdx.x;
  const int jobid = (lin & 7)*98 + (lin >> 3);
  const int reg = jobid % 49, n = jobid / 49;
  const int t = threadIdx.x, w8 = t>>6, g = (t>>4)&3, c16 = t&15;
  const int ry = reg/7, rx = reg%7;
  const size_t abase = ((size_t)(n*49 + reg))*8*2048;
  const int os1 = w8*16, os2 = os1 + 128;
  f32x4 acc[2][4] = {};
  for (int kc = 0; kc < 8; ++kc){
    const size_t wb = (size_t)kc*8192 + 8*g;
    short8 wh1 = *reinterpret_cast<const short8*>(wh_t + wb + (os1 + c16)*32);
    short8 wl1 = *reinterpret_cast<const short8*>(wl_t + wb + (os1 + c16)*32);
    short8 wh2 = *reinterpret_cast<const short8*>(wh_t + wb + (os2 + c16)*32);
    short8 wl2 = *reinterpret_cast<const short8*>(wl_t + wb + (os2 + c16)*32);
    #pragma unroll
    for (int pt = 0; pt < 4; ++pt){
      size_t off = abase + (size_t)kc*2048 + (pt*16 + c16)*32 + 8*g;
      short8 xh = *reinterpret_cast<const short8*>(ah_ + off);
      short8 xl = *reinterpret_cast<const short8*>(al_ + off);
      acc[0][pt] = MFMA(wh1, xh, acc[0][pt], 0, 0, 0);
      acc[0][pt] = MFMA(wh1, xl, acc[0][pt], 0, 0, 0);
      acc[0][pt] = MFMA(wl1, xh, acc[0][pt], 0, 0, 0);
      acc[1][pt] = MFMA(wh2, xh, acc[1][pt], 0, 0, 0);
      acc[1][pt] = MFMA(wh2, xl, acc[1][pt], 0, 0, 0);
      acc[1][pt] = MFMA(wl2, xh, acc[1][pt], 0, 0, 0);
    }
  }
  #pragma unroll
  for (int s = 0; s < 2; ++s){
    const int os = s ? os2 : os1;
    #pragma unroll
    for (int r = 0; r < 4; ++r){
      int o = os + 4*g + r;
      float bias = b_out[o];
      #pragma unroll
      for (int pt = 0; pt < 4; ++pt){
        int tok = pt*16 + c16;
        int p = (ry*8 + (tok>>3))*56 + rx*8 + (tok&7);
        out[((size_t)n*256 + o)*3136 + p] = acc[s][pt][r] + bias;
      }
    }
  }
}

extern "C" void kernel_launch(void* const* d_in, const int* in_sizes, int n_in,
                              void* d_out, int out_size, void* d_ws, size_t ws_size,
                              hipStream_t stream){
  const float* x      = (const float*)d_in[0];
  const float* w_qkv  = (const float*)d_in[1];
  const float* b_qkv  = (const float*)d_in[2];
  const float* w_lepe = (const float*)d_in[3];
  const float* b_lepe = (const float*)d_in[4];
  const float* w_out  = (const float*)d_in[5];
  const float* b_out  = (const float*)d_in[6];
  float* out = (float*)d_out;

  char* ws = (char*)d_ws;
  size_t off = 0;
  auto take = [&](size_t bytes)->char*{
    char* p = ws + off; off += (bytes + 255) & ~(size_t)255; return p;
  };
  const size_t TEN = (size_t)16*3136*256*2; // bf16 full tensor
  unsigned short* q_rm   = (unsigned short*)take(TEN);
  unsigned short* k_rm   = (unsigned short*)take(TEN);
  unsigned short* v_t    = (unsigned short*)take(TEN);
  unsigned short* att_hi = (unsigned short*)take(TEN);
  unsigned short* att_lo = (unsigned short*)take(TEN);
  float* xbar = (float*)take((size_t)16*49*256*4);
  float* q_r  = (float*)take((size_t)16*49*256*4);
  float* k_r  = (float*)take((size_t)16*49*256*4);
  int*   idxb = (int*)take((size_t)16*49*4*4);
  unsigned short* wqh_t = (unsigned short*)take((size_t)768*256*2);
  unsigned short* woh_t = (unsigned short*)take((size_t)256*256*2);
  unsigned short* wol_t = (unsigned short*)take((size_t)256*256*2);

  k_prep <<<dim3(1024), 256, 0, stream>>>(w_qkv, w_out, wqh_t, woh_t, wol_t);
  k_xbar <<<dim3(7, 16, 4), 256, 0, stream>>>(x, xbar);
  k_qrkr <<<dim3(8, 16, 7), 256, 0, stream>>>(xbar, w_qkv, b_qkv, q_r, k_r);
  k_topk <<<dim3(49, 16), 64, 0, stream>>>(q_r, k_r, idxb);
  k_qkv  <<<dim3(2352), 256, 0, stream>>>(x, wqh_t, b_qkv, q_rm, k_rm, v_t);
  k_attn <<<dim3(49, 8, 16), 256, 0, stream>>>(q_rm, k_rm, v_t, idxb, w_lepe, b_lepe, att_hi, att_lo);
  k_oproj<<<dim3(784), 512, 0, stream>>>(att_hi, att_lo, woh_t, wol_t, b_out, out);
}

// Round 21
// 241.899 us; speedup vs baseline: 1.0123x; 1.0123x over previous
//
#include <hip/hip_runtime.h>
#include <cstdint>

#define DEV __device__ __forceinline__

using short8 = __attribute__((ext_vector_type(8))) short;
using f32x4  = __attribute__((ext_vector_type(4))) float;

#define MFMA __builtin_amdgcn_mfma_f32_16x16x32_bf16

DEV float bf2f(unsigned short u){
  union { unsigned int i; float f; } v; v.i = ((unsigned int)u) << 16; return v.f;
}
DEV unsigned short f2bf(float f){
  union { float f; unsigned int i; } v; v.f = f;
  unsigned int x = v.i;
  return (unsigned short)((x + 0x7fffu + ((x >> 16) & 1u)) >> 16);
}
DEV unsigned int cvtpk(float a, float b){
  unsigned int r;
  asm("v_cvt_pk_bf16_f32 %0, %1, %2" : "=v"(r) : "v"(a), "v"(b));
  return r;
}

// ---------------- prep: transposed bf16 weights ----------------
__global__ __launch_bounds__(256) void k_prep(const float* __restrict__ w_qkv,
                                              const float* __restrict__ w_out,
                                              unsigned short* __restrict__ wqh_t,
                                              unsigned short* __restrict__ woh_t,
                                              unsigned short* __restrict__ wol_t){
  int i = blockIdx.x*256 + threadIdx.x;
  if (i < 196608){
    int o = i >> 8, c = i & 255, kc = c >> 5, kk = c & 31;
    wqh_t[kc*24576 + o*32 + kk] = f2bf(w_qkv[i]);
  } else {
    int j = i - 196608;
    if (j < 65536){
      int o = j >> 8, c = j & 255, kc = c >> 5, kk = c & 31;
      float v = w_out[j];
      unsigned short h = f2bf(v);
      int dst = kc*8192 + o*32 + kk;
      woh_t[dst] = h;
      wol_t[dst] = f2bf(v - bf2f(h));
    }
  }
}

// ---------------- q_r / k_r = W_{q,k} * xbar + b (fp32; 7-region chunks) ----------------
__global__ __launch_bounds__(256) void k_qrkr(const float* __restrict__ xbar,
                                              const float* __restrict__ w_qkv,
                                              const float* __restrict__ b_qkv,
                                              float* __restrict__ q_r,
                                              float* __restrict__ k_r){
  __shared__ float4 xb4[448];
  const int wb = blockIdx.x, n = blockIdx.y, rz = blockIdx.z, t = threadIdx.x;
  {
    const float4* src = (const float4*)(xbar + (size_t)n*12544) + rz*448;
    for (int i = t; i < 448; i += 256) xb4[i] = src[i];
  }
  const int wrow = wb*64 + (t>>2), kl = t&3;
  float4 wreg[16];
  {
    const float4* wsrc = (const float4*)(w_qkv + (size_t)wrow*256) + kl*16;
    #pragma unroll
    for (int i = 0; i < 16; ++i) wreg[i] = wsrc[i];
  }
  __syncthreads();
  const float bias = b_qkv[wrow];
  for (int rl = 0; rl < 7; ++rl){
    float s = 0.f;
    #pragma unroll
    for (int i = 0; i < 16; ++i){
      float4 a = wreg[i], b = xb4[rl*64 + kl*16 + i];
      s += a.x*b.x + a.y*b.y + a.z*b.z + a.w*b.w;
    }
    s += __shfl_xor(s, 1, 64);
    s += __shfl_xor(s, 2, 64);
    if (kl == 0){
      int reg = rz*7 + rl;
      if (wrow < 256) q_r[((size_t)n*49 + reg)*256 + wrow] = s + bias;
      else            k_r[((size_t)n*49 + reg)*256 + wrow - 256] = s + bias;
    }
  }
}

// ---------------- routing scores + top-4 (ties: lowest index first) ----------------
__global__ __launch_bounds__(64) void k_topk(const float* __restrict__ q_r,
                                             const float* __restrict__ k_r,
                                             int* __restrict__ idx){
  __shared__ float sc[49];
  const int qreg = blockIdx.x, n = blockIdx.y, l = threadIdx.x;
  const float* qrow = q_r + ((size_t)n*49 + qreg)*256;
  const float q0 = qrow[l], q1 = qrow[l+64], q2 = qrow[l+128], q3 = qrow[l+192];
  for (int kr = 0; kr < 49; ++kr){
    const float* krow = k_r + ((size_t)n*49 + kr)*256;
    float s = q0*krow[l] + q1*krow[l+64] + q2*krow[l+128] + q3*krow[l+192];
    #pragma unroll
    for (int m = 1; m < 64; m <<= 1) s += __shfl_xor(s, m, 64);
    if (l == 0) sc[kr] = s;
  }
  __syncthreads();
  if (l == 0){
    #pragma unroll
    for (int s = 0; s < 4; ++s){
      float best = -3.4e38f; int bi = 0;
      for (int kr = 0; kr < 49; ++kr) if (sc[kr] > best){ best = sc[kr]; bi = kr; }
      idx[((size_t)n*49 + qreg)*4 + s] = bi;
      sc[bi] = -3.4e38f;
    }
  }
}

// ---------------- qkv 1x1 conv GEMM + FUSED region-mean (z==0) ----------------
// x staged fp32->bf16 in LDS; z==0 blocks also emit xbar (fp32 sums from the
// same float4 loads: 4 toks/thread + 4 shfl_xor over the 16-lane c-group).
__global__ __launch_bounds__(256) void k_qkv(const float* __restrict__ x,
                                             const unsigned short* __restrict__ wqh_t,
                                             const float* __restrict__ b_qkv,
                                             unsigned short* __restrict__ q_rm,
                                             unsigned short* __restrict__ k_rm,
                                             unsigned short* __restrict__ v_t,
                                             float* __restrict__ xbar){
  __shared__ unsigned short xl[64*256]; // [tok][c], ushort idx ^= (tok&15)<<3
  const int lin = blockIdx.x;
  const int xcd = lin & 7, jj = lin >> 3;
  const int jobid = xcd*294 + jj;
  const int z = jobid % 3;
  const int pair = jobid / 3;
  const int reg = pair % 49, n = pair / 49;

  const int ry = reg/7, rx = reg%7;
  const int t = threadIdx.x, w = t>>6, g = (t>>4)&3, c16 = t&15;
  {
    const int pq = (t & 15)*4, cc = t >> 4;
    const int row = pq >> 3, col = pq & 7;
    const float* src = x + ((size_t)n*256 + cc)*3136 + (ry*8 + row)*56 + rx*8 + col;
    for (int ci = 0; ci < 16; ++ci){
      float4 v4 = *reinterpret_cast<const float4*>(src + (size_t)ci*16*3136);
      int c = ci*16 + cc;
      xl[((pq+0)*256 + c) ^ (((pq+0)&15)<<3)] = f2bf(v4.x);
      xl[((pq+1)*256 + c) ^ (((pq+1)&15)<<3)] = f2bf(v4.y);
      xl[((pq+2)*256 + c) ^ (((pq+2)&15)<<3)] = f2bf(v4.z);
      xl[((pq+3)*256 + c) ^ (((pq+3)&15)<<3)] = f2bf(v4.w);
      if (z == 0){
        float rs = v4.x + v4.y + v4.z + v4.w;   // 4 toks of channel c
        rs += __shfl_xor(rs, 1, 64);
        rs += __shfl_xor(rs, 2, 64);
        rs += __shfl_xor(rs, 4, 64);
        rs += __shfl_xor(rs, 8, 64);            // 16-lane group = all 64 toks
        if ((t & 15) == 0)
          xbar[((size_t)n*49 + reg)*256 + c] = rs * (1.0f/64.0f);
      }
    }
  }
  __syncthreads();
  const size_t rb = (size_t)(n*8)*49 + reg;
  const int osw = w*16;

  if (z < 2){
    f32x4 acc[4][4] = {};
    for (int kc = 0; kc < 8; ++kc){
      short8 xf[4];
      #pragma unroll
      for (int pt = 0; pt < 4; ++pt){
        int p = pt*16 + c16;
        xf[pt] = *reinterpret_cast<const short8*>(&xl[(p*256 + kc*32 + 8*g) ^ ((p&15)<<3)]);
      }
      #pragma unroll
      for (int oi = 0; oi < 4; ++oi){
        const int os = z*256 + oi*64 + osw;
        short8 wf = *reinterpret_cast<const short8*>(wqh_t + (size_t)kc*24576 + (os + c16)*32 + 8*g);
        #pragma unroll
        for (int pt = 0; pt < 4; ++pt)
          acc[oi][pt] = MFMA(xf[pt], wf, acc[oi][pt], 0, 0, 0);
      }
    }
    #pragma unroll
    for (int oi = 0; oi < 4; ++oi){
      const int o = z*256 + oi*64 + osw + c16;
      const float bias = b_qkv[o];
      const int oc = o & 255, hh = oc >> 5, dd = oc & 31;
      unsigned short* dst = ((z == 0) ? q_rm : k_rm) + (rb + hh*49)*2048 + dd;
      #pragma unroll
      for (int pt = 0; pt < 4; ++pt)
        #pragma unroll
        for (int r = 0; r < 4; ++r){
          int tok = pt*16 + 4*g + r;
          dst[tok*32] = f2bf(acc[oi][pt][r] + bias);
        }
    }
  } else {
    f32x4 acc[4][4] = {};
    for (int kc = 0; kc < 8; ++kc){
      short8 xf[4];
      #pragma unroll
      for (int pt = 0; pt < 4; ++pt){
        int p = pt*16 + c16;
        xf[pt] = *reinterpret_cast<const short8*>(&xl[(p*256 + kc*32 + 8*g) ^ ((p&15)<<3)]);
      }
      #pragma unroll
      for (int oi = 0; oi < 4; ++oi){
        const int os = oi*64 + osw;
        short8 wf = *reinterpret_cast<const short8*>(wqh_t + (size_t)kc*24576 + (512 + os + c16)*32 + 8*g);
        #pragma unroll
        for (int pt = 0; pt < 4; ++pt)
          acc[oi][pt] = MFMA(wf, xf[pt], acc[oi][pt], 0, 0, 0);
      }
    }
    #pragma unroll
    for (int oi = 0; oi < 4; ++oi){
      #pragma unroll
      for (int r = 0; r < 4; ++r){
        int c = oi*64 + osw + 4*g + r;
        const float bias = b_qkv[512 + c];
        int hh = c >> 5, ch = c & 31;
        unsigned short* dst = v_t + (rb + hh*49)*2048 + ch*32;
        #pragma unroll
        for (int pt = 0; pt < 4; ++pt){
          int tok = pt*16 + c16;
          dst[(tok>>5)*1024 + (tok&31)] = f2bf(acc[oi][pt][r] + bias);
        }
      }
    }
  }
}

// ---------------- attention + fused LEPE per (n, head, region) ----------------
// Two-half ONLINE softmax with per-query oacc rescale (R20, equal-perf/lower-reg).
__global__ __launch_bounds__(256, 4) void k_attn(const unsigned short* __restrict__ q_rm,
                                                 const unsigned short* __restrict__ k_rm,
                                                 const unsigned short* __restrict__ v_t,
                                                 const int* __restrict__ idx,
                                                 const float* __restrict__ w_lepe,
                                                 const float* __restrict__ b_lepe,
                                                 unsigned short* __restrict__ att_hi,
                                                 unsigned short* __restrict__ att_lo){
  __shared__ unsigned short halo[10*320];   // [dy][c][10] (x+1), bank-step 5 over c
  __shared__ float wl_s[288];
  __shared__ float bl_s[32];

  // XCD-aware remap
  const int lin = blockIdx.x + 49*(blockIdx.y + 8*blockIdx.z);
  const int xcd = lin & 7, j = lin >> 3;
  const int jq = j / 49;
  const int qreg = j - jq*49;
  const int hn = jq*8 + xcd;
  const int h = hn & 7, n = hn >> 3;

  const int t = threadIdx.x, w = t>>6, g = (t>>4)&3, c16 = t&15;
  const int ry = qreg/7, rx = qreg%7;
  const int gy0 = ry*8;

  int4 ridx = *reinterpret_cast<const int4*>(idx + ((size_t)n*49 + qreg)*4);
  int regs[4] = {ridx.x, ridx.y, ridx.z, ridx.w};

  const size_t hb = ((size_t)(n*8 + h))*49;

  // ---- stage LEPE weights + materialized halo rows ----
  wl_s[t < 288 ? t : 0] = w_lepe[h*288 + (t < 288 ? t : 0)];
  if (t < 32){
    wl_s[256 + t] = w_lepe[h*288 + 256 + t];
    bl_s[t] = b_lepe[h*32 + t];
  }
  #pragma unroll
  for (int pass = 0; pass < 2; ++pass){
    int s = pass ? (256 + t) : t;
    if (pass == 0 || t < 64){
      const int dy = s >> 5, c = s & 31;
      const int yy = gy0 + dy - 1;
      short8 inner = {0,0,0,0,0,0,0,0};
      unsigned short eL = 0, eR = 0;
      if (yy >= 0 && yy < 56){
        const int iry = yy >> 3, y7 = yy & 7;
        const size_t rowb = (size_t)(y7>>2)*1024 + c*32 + (y7&3)*8;
        inner = *reinterpret_cast<const short8*>(v_t + (hb + iry*7 + rx)*2048 + rowb);
        if (rx > 0) eL = v_t[(hb + iry*7 + rx - 1)*2048 + rowb + 7];
        if (rx < 6) eR = v_t[(hb + iry*7 + rx + 1)*2048 + rowb];
      }
      unsigned short* drow = &halo[dy*320 + c*10];
      drow[0] = eL;
      #pragma unroll
      for (int jj2 = 0; jj2 < 8; ++jj2) drow[1 + jj2] = (unsigned short)inner[jj2];
      drow[9] = eR;
    }
  }

  // ---- Q frag (B operand) ----
  const int qtok = w*16 + c16;
  short8 qf = *reinterpret_cast<const short8*>(q_rm + (hb + qreg)*2048 + qtok*32 + 8*g);

  const float scale2 = 0.1767766952966369f * 1.4426950408889634f; // d^-.5 * log2(e)
  const int srcA = (t & 15) | ((t & 16) << 1);   // 32*(g&1) + c16
  const int srcB = srcA + 16;
  const bool gsel = (t & 32) != 0;               // g>>1

  float m_run = -3.4e38f, su = 0.f;
  f32x4 oacc[2] = {};

  #pragma unroll
  for (int h2 = 0; h2 < 2; ++h2){
    // ---- QK^T for this half (regions regs[2*h2], regs[2*h2+1]) ----
    f32x4 s[8];
    #pragma unroll
    for (int f = 0; f < 8; ++f){
      const int tt = (f&3)*16 + c16;
      short8 kf = *reinterpret_cast<const short8*>(
          k_rm + (hb + regs[h2*2 + (f>>2)])*2048 + tt*32 + 8*g);
      f32x4 z = {0.f, 0.f, 0.f, 0.f};
      s[f] = MFMA(kf, qf, z, 0, 0, 0);
    }

    // ---- local max ----
    float ml = -3.4e38f;
    #pragma unroll
    for (int f = 0; f < 8; ++f)
      #pragma unroll
      for (int r = 0; r < 4; ++r) ml = fmaxf(ml, s[f][r]);
    ml = fmaxf(ml, __shfl_xor(ml, 16, 64));
    ml = fmaxf(ml, __shfl_xor(ml, 32, 64));

    // ---- online rescale (per-query for oacc) ----
    const float mnew = (h2 == 0) ? ml : fmaxf(m_run, ml);
    if (h2 != 0){
      const float resc = exp2f((m_run - mnew) * scale2);
      su *= resc;
      float rq[4];
      #pragma unroll
      for (int r = 0; r < 4; ++r)
        rq[r] = __shfl(resc, 4*g + r, 64);
      #pragma unroll
      for (int dt = 0; dt < 2; ++dt)
        #pragma unroll
        for (int r = 0; r < 4; ++r)
          oacc[dt][r] *= rq[r];
    }
    m_run = mnew;

    // ---- exp ----
    const float nms = -mnew * scale2;
    #pragma unroll
    for (int f = 0; f < 8; ++f)
      #pragma unroll
      for (int r = 0; r < 4; ++r){
        float e = exp2f(fmaf(s[f][r], scale2, nms));
        s[f][r] = e; su += e;
      }

    // ---- PV: A-frag assembled via bpermute exchange ----
    #pragma unroll
    for (int tcl = 0; tcl < 4; ++tcl){
      const int fb = (tcl>>1)*4 + (tcl&1)*2;
      unsigned int a0 = cvtpk(s[fb][0],   s[fb][1]);
      unsigned int a1 = cvtpk(s[fb][2],   s[fb][3]);
      unsigned int b0 = cvtpk(s[fb+1][0], s[fb+1][1]);
      unsigned int b1 = cvtpk(s[fb+1][2], s[fb+1][3]);
      unsigned int wa0 = __shfl((int)a0, srcA, 64), wa1 = __shfl((int)a1, srcA, 64);
      unsigned int wa2 = __shfl((int)a0, srcB, 64), wa3 = __shfl((int)a1, srcB, 64);
      unsigned int wb0 = __shfl((int)b0, srcA, 64), wb1 = __shfl((int)b1, srcA, 64);
      unsigned int wb2 = __shfl((int)b0, srcB, 64), wb3 = __shfl((int)b1, srcB, 64);
      union { unsigned int u[4]; short8 s8; } pfu;
      pfu.u[0] = gsel ? wb0 : wa0;
      pfu.u[1] = gsel ? wb1 : wa1;
      pfu.u[2] = gsel ? wb2 : wa2;
      pfu.u[3] = gsel ? wb3 : wa3;
      const size_t vb = (hb + regs[h2*2 + (tcl>>1)])*2048 + (tcl&1)*1024 + 8*g;
      #pragma unroll
      for (int dt = 0; dt < 2; ++dt){
        short8 vf = *reinterpret_cast<const short8*>(v_t + vb + (dt*16 + c16)*32);
        oacc[dt] = MFMA(pfu.s8, vf, oacc[dt], 0, 0, 0);
      }
    }
  }

  // ---- final sum reduce + inv ----
  su += __shfl_xor(su, 16, 64);
  su += __shfl_xor(su, 32, 64);
  const float inv_lane = __builtin_amdgcn_rcpf(su);
  float invq[4];
  #pragma unroll
  for (int r = 0; r < 4; ++r)
    invq[r] = __shfl(inv_lane, 4*g + r, 64);

  // ---- barrier: halo ready; LEPE epilogue = pure LDS loads + FMA ----
  __syncthreads();
  const int tok0 = w*16 + 4*g;
  const int ty = tok0>>3, tx0 = tok0&7;     // tx0 in {0,4}
  #pragma unroll
  for (int dt = 0; dt < 2; ++dt){
    const int cl = dt*16 + c16;
    float wl[9];
    #pragma unroll
    for (int kk = 0; kk < 9; ++kk) wl[kk] = wl_s[cl*9 + kk];
    const float bl = bl_s[cl];
    float vwin[3][6];
    #pragma unroll
    for (int dy = 0; dy < 3; ++dy){
      const unsigned short* hrow = &halo[(ty+dy)*320 + cl*10 + tx0];
      #pragma unroll
      for (int jj = 0; jj < 6; ++jj)
        vwin[dy][jj] = bf2f(hrow[jj]);
    }
    #pragma unroll
    for (int r = 0; r < 4; ++r){
      float a = fmaf(oacc[dt][r], invq[r], bl);
      #pragma unroll
      for (int dy = 0; dy < 3; ++dy)
        #pragma unroll
        for (int dx = 0; dx < 3; ++dx)
          a += wl[dy*3 + dx] * vwin[dy][r + dx];
      int tok = tok0 + r;
      size_t o = ((size_t)(n*49 + qreg)*8 + h)*2048 + tok*32 + dt*16 + c16;
      unsigned short hi = (unsigned short)cvtpk(a, a);
      att_hi[o] = hi;
      float alo = a - bf2f(hi);
      att_lo[o] = (unsigned short)cvtpk(alo, alo);
    }
  }
}

// ---------------- output projection (R14 exact: bf16x3; ah/al 16B loads; XCD write-merge) ----------------
__global__ __launch_bounds__(512) void k_oproj(const unsigned short* __restrict__ ah_,
                                               const unsigned short* __restrict__ al_,
                                               const unsigned short* __restrict__ wh_t,
                                               const unsigned short* __restrict__ wl_t,
                                               const float* __restrict__ b_out,
                                               float* __restrict__ out){
  // grid (784); jobid = xcd*98 + (lin>>3): each XCD owns 2 complete images
  const int lin = blockIdx.x;
  const int jobid = (lin & 7)*98 + (lin >> 3);
  const int reg = jobid % 49, n = jobid / 49;
  const int t = threadIdx.x, w8 = t>>6, g = (t>>4)&3, c16 = t&15;
  const int ry = reg/7, rx = reg%7;
  const size_t abase = ((size_t)(n*49 + reg))*8*2048;
  const int os1 = w8*16, os2 = os1 + 128;
  f32x4 acc[2][4] = {};
  for (int kc = 0; kc < 8; ++kc){
    const size_t wb = (size_t)kc*8192 + 8*g;
    short8 wh1 = *reinterpret_cast<const short8*>(wh_t + wb + (os1 + c16)*32);
    short8 wl1 = *reinterpret_cast<const short8*>(wl_t + wb + (os1 + c16)*32);
    short8 wh2 = *reinterpret_cast<const short8*>(wh_t + wb + (os2 + c16)*32);
    short8 wl2 = *reinterpret_cast<const short8*>(wl_t + wb + (os2 + c16)*32);
    #pragma unroll
    for (int pt = 0; pt < 4; ++pt){
      size_t off = abase + (size_t)kc*2048 + (pt*16 + c16)*32 + 8*g;
      short8 xh = *reinterpret_cast<const short8*>(ah_ + off);
      short8 xl = *reinterpret_cast<const short8*>(al_ + off);
      acc[0][pt] = MFMA(wh1, xh, acc[0][pt], 0, 0, 0);
      acc[0][pt] = MFMA(wh1, xl, acc[0][pt], 0, 0, 0);
      acc[0][pt] = MFMA(wl1, xh, acc[0][pt], 0, 0, 0);
      acc[1][pt] = MFMA(wh2, xh, acc[1][pt], 0, 0, 0);
      acc[1][pt] = MFMA(wh2, xl, acc[1][pt], 0, 0, 0);
      acc[1][pt] = MFMA(wl2, xh, acc[1][pt], 0, 0, 0);
    }
  }
  #pragma unroll
  for (int s = 0; s < 2; ++s){
    const int os = s ? os2 : os1;
    #pragma unroll
    for (int r = 0; r < 4; ++r){
      int o = os + 4*g + r;
      float bias = b_out[o];
      #pragma unroll
      for (int pt = 0; pt < 4; ++pt){
        int tok = pt*16 + c16;
        int p = (ry*8 + (tok>>3))*56 + rx*8 + (tok&7);
        out[((size_t)n*256 + o)*3136 + p] = acc[s][pt][r] + bias;
      }
    }
  }
}

extern "C" void kernel_launch(void* const* d_in, const int* in_sizes, int n_in,
                              void* d_out, int out_size, void* d_ws, size_t ws_size,
                              hipStream_t stream){
  const float* x      = (const float*)d_in[0];
  const float* w_qkv  = (const float*)d_in[1];
  const float* b_qkv  = (const float*)d_in[2];
  const float* w_lepe = (const float*)d_in[3];
  const float* b_lepe = (const float*)d_in[4];
  const float* w_out  = (const float*)d_in[5];
  const float* b_out  = (const float*)d_in[6];
  float* out = (float*)d_out;

  char* ws = (char*)d_ws;
  size_t off = 0;
  auto take = [&](size_t bytes)->char*{
    char* p = ws + off; off += (bytes + 255) & ~(size_t)255; return p;
  };
  const size_t TEN = (size_t)16*3136*256*2; // bf16 full tensor
  unsigned short* q_rm   = (unsigned short*)take(TEN);
  unsigned short* k_rm   = (unsigned short*)take(TEN);
  unsigned short* v_t    = (unsigned short*)take(TEN);
  unsigned short* att_hi = (unsigned short*)take(TEN);
  unsigned short* att_lo = (unsigned short*)take(TEN);
  float* xbar = (float*)take((size_t)16*49*256*4);
  float* q_r  = (float*)take((size_t)16*49*256*4);
  float* k_r  = (float*)take((size_t)16*49*256*4);
  int*   idxb = (int*)take((size_t)16*49*4*4);
  unsigned short* wqh_t = (unsigned short*)take((size_t)768*256*2);
  unsigned short* woh_t = (unsigned short*)take((size_t)256*256*2);
  unsigned short* wol_t = (unsigned short*)take((size_t)256*256*2);

  k_prep <<<dim3(1024), 256, 0, stream>>>(w_qkv, w_out, wqh_t, woh_t, wol_t);
  k_qkv  <<<dim3(2352), 256, 0, stream>>>(x, wqh_t, b_qkv, q_rm, k_rm, v_t, xbar);
  k_qrkr <<<dim3(8, 16, 7), 256, 0, stream>>>(xbar, w_qkv, b_qkv, q_r, k_r);
  k_topk <<<dim3(49, 16), 64, 0, stream>>>(q_r, k_r, idxb);
  k_attn <<<dim3(49, 8, 16), 256, 0, stream>>>(q_rm, k_rm, v_t, idxb, w_lepe, b_lepe, att_hi, att_lo);
  k_oproj<<<dim3(784), 512, 0, stream>>>(att_hi, att_lo, woh_t, wol_t, b_out, out);
}

// Round 22
// 236.597 us; speedup vs baseline: 1.0350x; 1.0224x over previous
//
#include <hip/hip_runtime.h>
#include <cstdint>

#define DEV __device__ __forceinline__

using short8 = __attribute__((ext_vector_type(8))) short;
using f32x4  = __attribute__((ext_vector_type(4))) float;

#define MFMA __builtin_amdgcn_mfma_f32_16x16x32_bf16

DEV float bf2f(unsigned short u){
  union { unsigned int i; float f; } v; v.i = ((unsigned int)u) << 16; return v.f;
}
DEV unsigned short f2bf(float f){
  union { float f; unsigned int i; } v; v.f = f;
  unsigned int x = v.i;
  return (unsigned short)((x + 0x7fffu + ((x >> 16) & 1u)) >> 16);
}
DEV unsigned int cvtpk(float a, float b){
  unsigned int r;
  asm("v_cvt_pk_bf16_f32 %0, %1, %2" : "=v"(r) : "v"(a), "v"(b));
  return r;
}

// ---------------- prep: transposed bf16 weights ----------------
__global__ __launch_bounds__(256) void k_prep(const float* __restrict__ w_qkv,
                                              const float* __restrict__ w_out,
                                              unsigned short* __restrict__ wqh_t,
                                              unsigned short* __restrict__ woh_t,
                                              unsigned short* __restrict__ wol_t){
  int i = blockIdx.x*256 + threadIdx.x;
  if (i < 196608){
    int o = i >> 8, c = i & 255, kc = c >> 5, kk = c & 31;
    wqh_t[kc*24576 + o*32 + kk] = f2bf(w_qkv[i]);
  } else {
    int j = i - 196608;
    if (j < 65536){
      int o = j >> 8, c = j & 255, kc = c >> 5, kk = c & 31;
      float v = w_out[j];
      unsigned short h = f2bf(v);
      int dst = kc*8192 + o*32 + kk;
      woh_t[dst] = h;
      wol_t[dst] = f2bf(v - bf2f(h));
    }
  }
}

// ---------------- q_r / k_r = W_{q,k} * xbar + b (fp32; 7-region chunks) ----------------
__global__ __launch_bounds__(256) void k_qrkr(const float* __restrict__ xbar,
                                              const float* __restrict__ w_qkv,
                                              const float* __restrict__ b_qkv,
                                              float* __restrict__ q_r,
                                              float* __restrict__ k_r){
  __shared__ float4 xb4[448];
  const int wb = blockIdx.x, n = blockIdx.y, rz = blockIdx.z, t = threadIdx.x;
  {
    const float4* src = (const float4*)(xbar + (size_t)n*12544) + rz*448;
    for (int i = t; i < 448; i += 256) xb4[i] = src[i];
  }
  const int wrow = wb*64 + (t>>2), kl = t&3;
  float4 wreg[16];
  {
    const float4* wsrc = (const float4*)(w_qkv + (size_t)wrow*256) + kl*16;
    #pragma unroll
    for (int i = 0; i < 16; ++i) wreg[i] = wsrc[i];
  }
  __syncthreads();
  const float bias = b_qkv[wrow];
  for (int rl = 0; rl < 7; ++rl){
    float s = 0.f;
    #pragma unroll
    for (int i = 0; i < 16; ++i){
      float4 a = wreg[i], b = xb4[rl*64 + kl*16 + i];
      s += a.x*b.x + a.y*b.y + a.z*b.z + a.w*b.w;
    }
    s += __shfl_xor(s, 1, 64);
    s += __shfl_xor(s, 2, 64);
    if (kl == 0){
      int reg = rz*7 + rl;
      if (wrow < 256) q_r[((size_t)n*49 + reg)*256 + wrow] = s + bias;
      else            k_r[((size_t)n*49 + reg)*256 + wrow - 256] = s + bias;
    }
  }
}

// ---------------- routing scores + top-4 (ties: lowest index first) ----------------
__global__ __launch_bounds__(64) void k_topk(const float* __restrict__ q_r,
                                             const float* __restrict__ k_r,
                                             int* __restrict__ idx){
  __shared__ float sc[49];
  const int qreg = blockIdx.x, n = blockIdx.y, l = threadIdx.x;
  const float* qrow = q_r + ((size_t)n*49 + qreg)*256;
  const float q0 = qrow[l], q1 = qrow[l+64], q2 = qrow[l+128], q3 = qrow[l+192];
  for (int kr = 0; kr < 49; ++kr){
    const float* krow = k_r + ((size_t)n*49 + kr)*256;
    float s = q0*krow[l] + q1*krow[l+64] + q2*krow[l+128] + q3*krow[l+192];
    #pragma unroll
    for (int m = 1; m < 64; m <<= 1) s += __shfl_xor(s, m, 64);
    if (l == 0) sc[kr] = s;
  }
  __syncthreads();
  if (l == 0){
    #pragma unroll
    for (int s = 0; s < 4; ++s){
      float best = -3.4e38f; int bi = 0;
      for (int kr = 0; kr < 49; ++kr) if (sc[kr] > best){ best = sc[kr]; bi = kr; }
      idx[((size_t)n*49 + qreg)*4 + s] = bi;
      sc[bi] = -3.4e38f;
    }
  }
}

// ---------------- qkv 1x1 conv GEMM + fused region-mean (post-loop reduce) ----------------
// Staging loop unrolled: 16 float4 loads pipeline with no DS deps; per-ci
// 4-tok partials kept in rs[16] registers; z==0 reduces AFTER the loop.
__global__ __launch_bounds__(256) void k_qkv(const float* __restrict__ x,
                                             const unsigned short* __restrict__ wqh_t,
                                             const float* __restrict__ b_qkv,
                                             unsigned short* __restrict__ q_rm,
                                             unsigned short* __restrict__ k_rm,
                                             unsigned short* __restrict__ v_t,
                                             float* __restrict__ xbar){
  __shared__ unsigned short xl[64*256]; // [tok][c], ushort idx ^= (tok&15)<<3
  const int lin = blockIdx.x;
  const int xcd = lin & 7, jj = lin >> 3;
  const int jobid = xcd*294 + jj;
  const int z = jobid % 3;
  const int pair = jobid / 3;
  const int reg = pair % 49, n = pair / 49;

  const int ry = reg/7, rx = reg%7;
  const int t = threadIdx.x, w = t>>6, g = (t>>4)&3, c16 = t&15;
  {
    const int pq = (t & 15)*4, cc = t >> 4;
    const int row = pq >> 3, col = pq & 7;
    const float* src = x + ((size_t)n*256 + cc)*3136 + (ry*8 + row)*56 + rx*8 + col;
    float rs[16];
    #pragma unroll
    for (int ci = 0; ci < 16; ++ci){
      float4 v4 = *reinterpret_cast<const float4*>(src + (size_t)ci*16*3136);
      int c = ci*16 + cc;
      xl[((pq+0)*256 + c) ^ (((pq+0)&15)<<3)] = f2bf(v4.x);
      xl[((pq+1)*256 + c) ^ (((pq+1)&15)<<3)] = f2bf(v4.y);
      xl[((pq+2)*256 + c) ^ (((pq+2)&15)<<3)] = f2bf(v4.z);
      xl[((pq+3)*256 + c) ^ (((pq+3)&15)<<3)] = f2bf(v4.w);
      rs[ci] = v4.x + v4.y + v4.z + v4.w;
    }
    if (z == 0){
      // 64 independent shfl chains, fully pipelined (no load deps)
      #pragma unroll
      for (int ci = 0; ci < 16; ++ci){
        float r = rs[ci];
        r += __shfl_xor(r, 1, 64);
        r += __shfl_xor(r, 2, 64);
        r += __shfl_xor(r, 4, 64);
        r += __shfl_xor(r, 8, 64);
        if ((t & 15) == 0)
          xbar[((size_t)n*49 + reg)*256 + ci*16 + (t>>4)] = r * (1.0f/64.0f);
      }
    }
  }
  __syncthreads();
  const size_t rb = (size_t)(n*8)*49 + reg;
  const int osw = w*16;

  if (z < 2){
    f32x4 acc[4][4] = {};
    for (int kc = 0; kc < 8; ++kc){
      short8 xf[4];
      #pragma unroll
      for (int pt = 0; pt < 4; ++pt){
        int p = pt*16 + c16;
        xf[pt] = *reinterpret_cast<const short8*>(&xl[(p*256 + kc*32 + 8*g) ^ ((p&15)<<3)]);
      }
      #pragma unroll
      for (int oi = 0; oi < 4; ++oi){
        const int os = z*256 + oi*64 + osw;
        short8 wf = *reinterpret_cast<const short8*>(wqh_t + (size_t)kc*24576 + (os + c16)*32 + 8*g);
        #pragma unroll
        for (int pt = 0; pt < 4; ++pt)
          acc[oi][pt] = MFMA(xf[pt], wf, acc[oi][pt], 0, 0, 0);
      }
    }
    #pragma unroll
    for (int oi = 0; oi < 4; ++oi){
      const int o = z*256 + oi*64 + osw + c16;
      const float bias = b_qkv[o];
      const int oc = o & 255, hh = oc >> 5, dd = oc & 31;
      unsigned short* dst = ((z == 0) ? q_rm : k_rm) + (rb + hh*49)*2048 + dd;
      #pragma unroll
      for (int pt = 0; pt < 4; ++pt)
        #pragma unroll
        for (int r = 0; r < 4; ++r){
          int tok = pt*16 + 4*g + r;
          dst[tok*32] = f2bf(acc[oi][pt][r] + bias);
        }
    }
  } else {
    f32x4 acc[4][4] = {};
    for (int kc = 0; kc < 8; ++kc){
      short8 xf[4];
      #pragma unroll
      for (int pt = 0; pt < 4; ++pt){
        int p = pt*16 + c16;
        xf[pt] = *reinterpret_cast<const short8*>(&xl[(p*256 + kc*32 + 8*g) ^ ((p&15)<<3)]);
      }
      #pragma unroll
      for (int oi = 0; oi < 4; ++oi){
        const int os = oi*64 + osw;
        short8 wf = *reinterpret_cast<const short8*>(wqh_t + (size_t)kc*24576 + (512 + os + c16)*32 + 8*g);
        #pragma unroll
        for (int pt = 0; pt < 4; ++pt)
          acc[oi][pt] = MFMA(wf, xf[pt], acc[oi][pt], 0, 0, 0);
      }
    }
    #pragma unroll
    for (int oi = 0; oi < 4; ++oi){
      #pragma unroll
      for (int r = 0; r < 4; ++r){
        int c = oi*64 + osw + 4*g + r;
        const float bias = b_qkv[512 + c];
        int hh = c >> 5, ch = c & 31;
        unsigned short* dst = v_t + (rb + hh*49)*2048 + ch*32;
        #pragma unroll
        for (int pt = 0; pt < 4; ++pt){
          int tok = pt*16 + c16;
          dst[(tok>>5)*1024 + (tok&31)] = f2bf(acc[oi][pt][r] + bias);
        }
      }
    }
  }
}

// ---------------- attention + fused LEPE per (n, head, region) ----------------
// Two-half ONLINE softmax with per-query oacc rescale (R20, equal-perf/lower-reg).
__global__ __launch_bounds__(256, 4) void k_attn(const unsigned short* __restrict__ q_rm,
                                                 const unsigned short* __restrict__ k_rm,
                                                 const unsigned short* __restrict__ v_t,
                                                 const int* __restrict__ idx,
                                                 const float* __restrict__ w_lepe,
                                                 const float* __restrict__ b_lepe,
                                                 unsigned short* __restrict__ att_hi,
                                                 unsigned short* __restrict__ att_lo){
  __shared__ unsigned short halo[10*320];   // [dy][c][10] (x+1), bank-step 5 over c
  __shared__ float wl_s[288];
  __shared__ float bl_s[32];

  // XCD-aware remap
  const int lin = blockIdx.x + 49*(blockIdx.y + 8*blockIdx.z);
  const int xcd = lin & 7, j = lin >> 3;
  const int jq = j / 49;
  const int qreg = j - jq*49;
  const int hn = jq*8 + xcd;
  const int h = hn & 7, n = hn >> 3;

  const int t = threadIdx.x, w = t>>6, g = (t>>4)&3, c16 = t&15;
  const int ry = qreg/7, rx = qreg%7;
  const int gy0 = ry*8;

  int4 ridx = *reinterpret_cast<const int4*>(idx + ((size_t)n*49 + qreg)*4);
  int regs[4] = {ridx.x, ridx.y, ridx.z, ridx.w};

  const size_t hb = ((size_t)(n*8 + h))*49;

  // ---- stage LEPE weights + materialized halo rows ----
  wl_s[t < 288 ? t : 0] = w_lepe[h*288 + (t < 288 ? t : 0)];
  if (t < 32){
    wl_s[256 + t] = w_lepe[h*288 + 256 + t];
    bl_s[t] = b_lepe[h*32 + t];
  }
  #pragma unroll
  for (int pass = 0; pass < 2; ++pass){
    int s = pass ? (256 + t) : t;
    if (pass == 0 || t < 64){
      const int dy = s >> 5, c = s & 31;
      const int yy = gy0 + dy - 1;
      short8 inner = {0,0,0,0,0,0,0,0};
      unsigned short eL = 0, eR = 0;
      if (yy >= 0 && yy < 56){
        const int iry = yy >> 3, y7 = yy & 7;
        const size_t rowb = (size_t)(y7>>2)*1024 + c*32 + (y7&3)*8;
        inner = *reinterpret_cast<const short8*>(v_t + (hb + iry*7 + rx)*2048 + rowb);
        if (rx > 0) eL = v_t[(hb + iry*7 + rx - 1)*2048 + rowb + 7];
        if (rx < 6) eR = v_t[(hb + iry*7 + rx + 1)*2048 + rowb];
      }
      unsigned short* drow = &halo[dy*320 + c*10];
      drow[0] = eL;
      #pragma unroll
      for (int jj2 = 0; jj2 < 8; ++jj2) drow[1 + jj2] = (unsigned short)inner[jj2];
      drow[9] = eR;
    }
  }

  // ---- Q frag (B operand) ----
  const int qtok = w*16 + c16;
  short8 qf = *reinterpret_cast<const short8*>(q_rm + (hb + qreg)*2048 + qtok*32 + 8*g);

  const float scale2 = 0.1767766952966369f * 1.4426950408889634f; // d^-.5 * log2(e)
  const int srcA = (t & 15) | ((t & 16) << 1);   // 32*(g&1) + c16
  const int srcB = srcA + 16;
  const bool gsel = (t & 32) != 0;               // g>>1

  float m_run = -3.4e38f, su = 0.f;
  f32x4 oacc[2] = {};

  #pragma unroll
  for (int h2 = 0; h2 < 2; ++h2){
    // ---- QK^T for this half (regions regs[2*h2], regs[2*h2+1]) ----
    f32x4 s[8];
    #pragma unroll
    for (int f = 0; f < 8; ++f){
      const int tt = (f&3)*16 + c16;
      short8 kf = *reinterpret_cast<const short8*>(
          k_rm + (hb + regs[h2*2 + (f>>2)])*2048 + tt*32 + 8*g);
      f32x4 z = {0.f, 0.f, 0.f, 0.f};
      s[f] = MFMA(kf, qf, z, 0, 0, 0);
    }

    // ---- local max ----
    float ml = -3.4e38f;
    #pragma unroll
    for (int f = 0; f < 8; ++f)
      #pragma unroll
      for (int r = 0; r < 4; ++r) ml = fmaxf(ml, s[f][r]);
    ml = fmaxf(ml, __shfl_xor(ml, 16, 64));
    ml = fmaxf(ml, __shfl_xor(ml, 32, 64));

    // ---- online rescale (per-query for oacc) ----
    const float mnew = (h2 == 0) ? ml : fmaxf(m_run, ml);
    if (h2 != 0){
      const float resc = exp2f((m_run - mnew) * scale2);
      su *= resc;
      float rq[4];
      #pragma unroll
      for (int r = 0; r < 4; ++r)
        rq[r] = __shfl(resc, 4*g + r, 64);
      #pragma unroll
      for (int dt = 0; dt < 2; ++dt)
        #pragma unroll
        for (int r = 0; r < 4; ++r)
          oacc[dt][r] *= rq[r];
    }
    m_run = mnew;

    // ---- exp ----
    const float nms = -mnew * scale2;
    #pragma unroll
    for (int f = 0; f < 8; ++f)
      #pragma unroll
      for (int r = 0; r < 4; ++r){
        float e = exp2f(fmaf(s[f][r], scale2, nms));
        s[f][r] = e; su += e;
      }

    // ---- PV: A-frag assembled via bpermute exchange ----
    #pragma unroll
    for (int tcl = 0; tcl < 4; ++tcl){
      const int fb = (tcl>>1)*4 + (tcl&1)*2;
      unsigned int a0 = cvtpk(s[fb][0],   s[fb][1]);
      unsigned int a1 = cvtpk(s[fb][2],   s[fb][3]);
      unsigned int b0 = cvtpk(s[fb+1][0], s[fb+1][1]);
      unsigned int b1 = cvtpk(s[fb+1][2], s[fb+1][3]);
      unsigned int wa0 = __shfl((int)a0, srcA, 64), wa1 = __shfl((int)a1, srcA, 64);
      unsigned int wa2 = __shfl((int)a0, srcB, 64), wa3 = __shfl((int)a1, srcB, 64);
      unsigned int wb0 = __shfl((int)b0, srcA, 64), wb1 = __shfl((int)b1, srcA, 64);
      unsigned int wb2 = __shfl((int)b0, srcB, 64), wb3 = __shfl((int)b1, srcB, 64);
      union { unsigned int u[4]; short8 s8; } pfu;
      pfu.u[0] = gsel ? wb0 : wa0;
      pfu.u[1] = gsel ? wb1 : wa1;
      pfu.u[2] = gsel ? wb2 : wa2;
      pfu.u[3] = gsel ? wb3 : wa3;
      const size_t vb = (hb + regs[h2*2 + (tcl>>1)])*2048 + (tcl&1)*1024 + 8*g;
      #pragma unroll
      for (int dt = 0; dt < 2; ++dt){
        short8 vf = *reinterpret_cast<const short8*>(v_t + vb + (dt*16 + c16)*32);
        oacc[dt] = MFMA(pfu.s8, vf, oacc[dt], 0, 0, 0);
      }
    }
  }

  // ---- final sum reduce + inv ----
  su += __shfl_xor(su, 16, 64);
  su += __shfl_xor(su, 32, 64);
  const float inv_lane = __builtin_amdgcn_rcpf(su);
  float invq[4];
  #pragma unroll
  for (int r = 0; r < 4; ++r)
    invq[r] = __shfl(inv_lane, 4*g + r, 64);

  // ---- barrier: halo ready; LEPE epilogue = pure LDS loads + FMA ----
  __syncthreads();
  const int tok0 = w*16 + 4*g;
  const int ty = tok0>>3, tx0 = tok0&7;     // tx0 in {0,4}
  #pragma unroll
  for (int dt = 0; dt < 2; ++dt){
    const int cl = dt*16 + c16;
    float wl[9];
    #pragma unroll
    for (int kk = 0; kk < 9; ++kk) wl[kk] = wl_s[cl*9 + kk];
    const float bl = bl_s[cl];
    float vwin[3][6];
    #pragma unroll
    for (int dy = 0; dy < 3; ++dy){
      const unsigned short* hrow = &halo[(ty+dy)*320 + cl*10 + tx0];
      #pragma unroll
      for (int jj = 0; jj < 6; ++jj)
        vwin[dy][jj] = bf2f(hrow[jj]);
    }
    #pragma unroll
    for (int r = 0; r < 4; ++r){
      float a = fmaf(oacc[dt][r], invq[r], bl);
      #pragma unroll
      for (int dy = 0; dy < 3; ++dy)
        #pragma unroll
        for (int dx = 0; dx < 3; ++dx)
          a += wl[dy*3 + dx] * vwin[dy][r + dx];
      int tok = tok0 + r;
      size_t o = ((size_t)(n*49 + qreg)*8 + h)*2048 + tok*32 + dt*16 + c16;
      unsigned short hi = (unsigned short)cvtpk(a, a);
      att_hi[o] = hi;
      float alo = a - bf2f(hi);
      att_lo[o] = (unsigned short)cvtpk(alo, alo);
    }
  }
}

// ---------------- output projection (R14 exact: bf16x3; ah/al 16B loads; XCD write-merge) ----------------
__global__ __launch_bounds__(512) void k_oproj(const unsigned short* __restrict__ ah_,
                                               const unsigned short* __restrict__ al_,
                                               const unsigned short* __restrict__ wh_t,
                                               const unsigned short* __restrict__ wl_t,
                                               const float* __restrict__ b_out,
                                               float* __restrict__ out){
  // grid (784); jobid = xcd*98 + (lin>>3): each XCD owns 2 complete images
  const int lin = blockIdx.x;
  const int jobid = (lin & 7)*98 + (lin >> 3);
  const int reg = jobid % 49, n = jobid / 49;
  const int t = threadIdx.x, w8 = t>>6, g = (t>>4)&3, c16 = t&15;
  const int ry = reg/7, rx = reg%7;
  const size_t abase = ((size_t)(n*49 + reg))*8*2048;
  const int os1 = w8*16, os2 = os1 + 128;
  f32x4 acc[2][4] = {};
  for (int kc = 0; kc < 8; ++kc){
    const size_t wb = (size_t)kc*8192 + 8*g;
    short8 wh1 = *reinterpret_cast<const short8*>(wh_t + wb + (os1 + c16)*32);
    short8 wl1 = *reinterpret_cast<const short8*>(wl_t + wb + (os1 + c16)*32);
    short8 wh2 = *reinterpret_cast<const short8*>(wh_t + wb + (os2 + c16)*32);
    short8 wl2 = *reinterpret_cast<const short8*>(wl_t + wb + (os2 + c16)*32);
    #pragma unroll
    for (int pt = 0; pt < 4; ++pt){
      size_t off = abase + (size_t)kc*2048 + (pt*16 + c16)*32 + 8*g;
      short8 xh = *reinterpret_cast<const short8*>(ah_ + off);
      short8 xl = *reinterpret_cast<const short8*>(al_ + off);
      acc[0][pt] = MFMA(wh1, xh, acc[0][pt], 0, 0, 0);
      acc[0][pt] = MFMA(wh1, xl, acc[0][pt], 0, 0, 0);
      acc[0][pt] = MFMA(wl1, xh, acc[0][pt], 0, 0, 0);
      acc[1][pt] = MFMA(wh2, xh, acc[1][pt], 0, 0, 0);
      acc[1][pt] = MFMA(wh2, xl, acc[1][pt], 0, 0, 0);
      acc[1][pt] = MFMA(wl2, xh, acc[1][pt], 0, 0, 0);
    }
  }
  #pragma unroll
  for (int s = 0; s < 2; ++s){
    const int os = s ? os2 : os1;
    #pragma unroll
    for (int r = 0; r < 4; ++r){
      int o = os + 4*g + r;
      float bias = b_out[o];
      #pragma unroll
      for (int pt = 0; pt < 4; ++pt){
        int tok = pt*16 + c16;
        int p = (ry*8 + (tok>>3))*56 + rx*8 + (tok&7);
        out[((size_t)n*256 + o)*3136 + p] = acc[s][pt][r] + bias;
      }
    }
  }
}

extern "C" void kernel_launch(void* const* d_in, const int* in_sizes, int n_in,
                              void* d_out, int out_size, void* d_ws, size_t ws_size,
                              hipStream_t stream){
  const float* x      = (const float*)d_in[0];
  const float* w_qkv  = (const float*)d_in[1];
  const float* b_qkv  = (const float*)d_in[2];
  const float* w_lepe = (const float*)d_in[3];
  const float* b_lepe = (const float*)d_in[4];
  const float* w_out  = (const float*)d_in[5];
  const float* b_out  = (const float*)d_in[6];
  float* out = (float*)d_out;

  char* ws = (char*)d_ws;
  size_t off = 0;
  auto take = [&](size_t bytes)->char*{
    char* p = ws + off; off += (bytes + 255) & ~(size_t)255; return p;
  };
  const size_t TEN = (size_t)16*3136*256*2; // bf16 full tensor
  unsigned short* q_rm   = (unsigned short*)take(TEN);
  unsigned short* k_rm   = (unsigned short*)take(TEN);
  unsigned short* v_t    = (unsigned short*)take(TEN);
  unsigned short* att_hi = (unsigned short*)take(TEN);
  unsigned short* att_lo = (unsigned short*)take(TEN);
  float* xbar = (float*)take((size_t)16*49*256*4);
  float* q_r  = (float*)take((size_t)16*49*256*4);
  float* k_r  = (float*)take((size_t)16*49*256*4);
  int*   idxb = (int*)take((size_t)16*49*4*4);
  unsigned short* wqh_t = (unsigned short*)take((size_t)768*256*2);
  unsigned short* woh_t = (unsigned short*)take((size_t)256*256*2);
  unsigned short* wol_t = (unsigned short*)take((size_t)256*256*2);

  k_prep <<<dim3(1024), 256, 0, stream>>>(w_qkv, w_out, wqh_t, woh_t, wol_t);
  k_qkv  <<<dim3(2352), 256, 0, stream>>>(x, wqh_t, b_qkv, q_rm, k_rm, v_t, xbar);
  k_qrkr <<<dim3(8, 16, 7), 256, 0, stream>>>(xbar, w_qkv, b_qkv, q_r, k_r);
  k_topk <<<dim3(49, 16), 64, 0, stream>>>(q_r, k_r, idxb);
  k_attn <<<dim3(49, 8, 16), 256, 0, stream>>>(q_rm, k_rm, v_t, idxb, w_lepe, b_lepe, att_hi, att_lo);
  k_oproj<<<dim3(784), 512, 0, stream>>>(att_hi, att_lo, woh_t, wol_t, b_out, out);
}

// Round 23
// 232.523 us; speedup vs baseline: 1.0531x; 1.0175x over previous
//
#include <hip/hip_runtime.h>
#include <cstdint>

#define DEV __device__ __forceinline__

using short8 = __attribute__((ext_vector_type(8))) short;
using f32x4  = __attribute__((ext_vector_type(4))) float;

#define MFMA __builtin_amdgcn_mfma_f32_16x16x32_bf16

DEV float bf2f(unsigned short u){
  union { unsigned int i; float f; } v; v.i = ((unsigned int)u) << 16; return v.f;
}
DEV unsigned short f2bf(float f){
  union { float f; unsigned int i; } v; v.f = f;
  unsigned int x = v.i;
  return (unsigned short)((x + 0x7fffu + ((x >> 16) & 1u)) >> 16);
}
DEV unsigned int cvtpk(float a, float b){
  unsigned int r;
  asm("v_cvt_pk_bf16_f32 %0, %1, %2" : "=v"(r) : "v"(a), "v"(b));
  return r;
}

// ---------------- prep: transposed bf16 weights ----------------
__global__ __launch_bounds__(256) void k_prep(const float* __restrict__ w_qkv,
                                              const float* __restrict__ w_out,
                                              unsigned short* __restrict__ wqh_t,
                                              unsigned short* __restrict__ woh_t,
                                              unsigned short* __restrict__ wol_t){
  int i = blockIdx.x*256 + threadIdx.x;
  if (i < 196608){
    int o = i >> 8, c = i & 255, kc = c >> 5, kk = c & 31;
    wqh_t[kc*24576 + o*32 + kk] = f2bf(w_qkv[i]);
  } else {
    int j = i - 196608;
    if (j < 65536){
      int o = j >> 8, c = j & 255, kc = c >> 5, kk = c & 31;
      float v = w_out[j];
      unsigned short h = f2bf(v);
      int dst = kc*8192 + o*32 + kk;
      woh_t[dst] = h;
      wol_t[dst] = f2bf(v - bf2f(h));
    }
  }
}

// ---------------- q_r / k_r = W_{q,k} * xbar + b (fp32; 7-region chunks) ----------------
__global__ __launch_bounds__(256) void k_qrkr(const float* __restrict__ xbar,
                                              const float* __restrict__ w_qkv,
                                              const float* __restrict__ b_qkv,
                                              float* __restrict__ q_r,
                                              float* __restrict__ k_r){
  __shared__ float4 xb4[448];
  const int wb = blockIdx.x, n = blockIdx.y, rz = blockIdx.z, t = threadIdx.x;
  {
    const float4* src = (const float4*)(xbar + (size_t)n*12544) + rz*448;
    for (int i = t; i < 448; i += 256) xb4[i] = src[i];
  }
  const int wrow = wb*64 + (t>>2), kl = t&3;
  float4 wreg[16];
  {
    const float4* wsrc = (const float4*)(w_qkv + (size_t)wrow*256) + kl*16;
    #pragma unroll
    for (int i = 0; i < 16; ++i) wreg[i] = wsrc[i];
  }
  __syncthreads();
  const float bias = b_qkv[wrow];
  for (int rl = 0; rl < 7; ++rl){
    float s = 0.f;
    #pragma unroll
    for (int i = 0; i < 16; ++i){
      float4 a = wreg[i], b = xb4[rl*64 + kl*16 + i];
      s += a.x*b.x + a.y*b.y + a.z*b.z + a.w*b.w;
    }
    s += __shfl_xor(s, 1, 64);
    s += __shfl_xor(s, 2, 64);
    if (kl == 0){
      int reg = rz*7 + rl;
      if (wrow < 256) q_r[((size_t)n*49 + reg)*256 + wrow] = s + bias;
      else            k_r[((size_t)n*49 + reg)*256 + wrow - 256] = s + bias;
    }
  }
}

// ---------------- routing scores + top-4 (ties: lowest index first) ----------------
__global__ __launch_bounds__(64) void k_topk(const float* __restrict__ q_r,
                                             const float* __restrict__ k_r,
                                             int* __restrict__ idx){
  __shared__ float sc[49];
  const int qreg = blockIdx.x, n = blockIdx.y, l = threadIdx.x;
  const float* qrow = q_r + ((size_t)n*49 + qreg)*256;
  const float q0 = qrow[l], q1 = qrow[l+64], q2 = qrow[l+128], q3 = qrow[l+192];
  for (int kr = 0; kr < 49; ++kr){
    const float* krow = k_r + ((size_t)n*49 + kr)*256;
    float s = q0*krow[l] + q1*krow[l+64] + q2*krow[l+128] + q3*krow[l+192];
    #pragma unroll
    for (int m = 1; m < 64; m <<= 1) s += __shfl_xor(s, m, 64);
    if (l == 0) sc[kr] = s;
  }
  __syncthreads();
  if (l == 0){
    #pragma unroll
    for (int s = 0; s < 4; ++s){
      float best = -3.4e38f; int bi = 0;
      for (int kr = 0; kr < 49; ++kr) if (sc[kr] > best){ best = sc[kr]; bi = kr; }
      idx[((size_t)n*49 + qreg)*4 + s] = bi;
      sc[bi] = -3.4e38f;
    }
  }
}

// ---------------- qkv 1x1 conv GEMM: 6-way o-split + fused region-mean ----------------
// grid 4704 = 49reg x 16n x 6(z). z>>1: 0=q,1=k,2=v; z&1: which 128-o half.
// acc[2][4]=32 AGPR; all 6 siblings of a (reg,n) XCD-co-located -> x L2-shared.
__global__ __launch_bounds__(256) void k_qkv(const float* __restrict__ x,
                                             const unsigned short* __restrict__ wqh_t,
                                             const float* __restrict__ b_qkv,
                                             unsigned short* __restrict__ q_rm,
                                             unsigned short* __restrict__ k_rm,
                                             unsigned short* __restrict__ v_t,
                                             float* __restrict__ xbar){
  __shared__ unsigned short xl[64*256]; // [tok][c], ushort idx ^= (tok&15)<<3
  const int lin = blockIdx.x;
  const int xcd = lin & 7, jj = lin >> 3;        // jj in [0,588)
  const int jobid = xcd*588 + jj;
  const int z = jobid % 6;
  const int pair = jobid / 6;                    // xcd*98 + jj/6
  const int reg = pair % 49, n = pair / 49;
  const int kind = z >> 1, half = z & 1;

  const int ry = reg/7, rx = reg%7;
  const int t = threadIdx.x, w = t>>6, g = (t>>4)&3, c16 = t&15;
  {
    const int pq = (t & 15)*4, cc = t >> 4;
    const int row = pq >> 3, col = pq & 7;
    const float* src = x + ((size_t)n*256 + cc)*3136 + (ry*8 + row)*56 + rx*8 + col;
    float rs[16];
    #pragma unroll
    for (int ci = 0; ci < 16; ++ci){
      float4 v4 = *reinterpret_cast<const float4*>(src + (size_t)ci*16*3136);
      int c = ci*16 + cc;
      xl[((pq+0)*256 + c) ^ (((pq+0)&15)<<3)] = f2bf(v4.x);
      xl[((pq+1)*256 + c) ^ (((pq+1)&15)<<3)] = f2bf(v4.y);
      xl[((pq+2)*256 + c) ^ (((pq+2)&15)<<3)] = f2bf(v4.z);
      xl[((pq+3)*256 + c) ^ (((pq+3)&15)<<3)] = f2bf(v4.w);
      rs[ci] = v4.x + v4.y + v4.z + v4.w;
    }
    if (z == 0){
      #pragma unroll
      for (int ci = 0; ci < 16; ++ci){
        float r = rs[ci];
        r += __shfl_xor(r, 1, 64);
        r += __shfl_xor(r, 2, 64);
        r += __shfl_xor(r, 4, 64);
        r += __shfl_xor(r, 8, 64);
        if ((t & 15) == 0)
          xbar[((size_t)n*49 + reg)*256 + ci*16 + (t>>4)] = r * (1.0f/64.0f);
      }
    }
  }
  __syncthreads();
  const size_t rb = (size_t)(n*8)*49 + reg;
  const int osw = w*16;

  if (kind < 2){
    // ---- q (kind=0) or k (kind=1): 2 o-tiles of the chosen half ----
    f32x4 acc[2][4] = {};
    for (int kc = 0; kc < 8; ++kc){
      short8 xf[4];
      #pragma unroll
      for (int pt = 0; pt < 4; ++pt){
        int p = pt*16 + c16;
        xf[pt] = *reinterpret_cast<const short8*>(&xl[(p*256 + kc*32 + 8*g) ^ ((p&15)<<3)]);
      }
      #pragma unroll
      for (int oi = 0; oi < 2; ++oi){
        const int os = kind*256 + (half*2 + oi)*64 + osw;
        short8 wf = *reinterpret_cast<const short8*>(wqh_t + (size_t)kc*24576 + (os + c16)*32 + 8*g);
        #pragma unroll
        for (int pt = 0; pt < 4; ++pt)
          acc[oi][pt] = MFMA(xf[pt], wf, acc[oi][pt], 0, 0, 0);
      }
    }
    #pragma unroll
    for (int oi = 0; oi < 2; ++oi){
      const int o = kind*256 + (half*2 + oi)*64 + osw + c16;
      const float bias = b_qkv[o];
      const int oc = o & 255, hh = oc >> 5, dd = oc & 31;
      unsigned short* dst = ((kind == 0) ? q_rm : k_rm) + (rb + hh*49)*2048 + dd;
      #pragma unroll
      for (int pt = 0; pt < 4; ++pt)
        #pragma unroll
        for (int r = 0; r < 4; ++r){
          int tok = pt*16 + 4*g + r;
          dst[tok*32] = f2bf(acc[oi][pt][r] + bias);
        }
    }
  } else {
    // ---- v: 2 o-tiles of the chosen half, swapped operand order ----
    f32x4 acc[2][4] = {};
    for (int kc = 0; kc < 8; ++kc){
      short8 xf[4];
      #pragma unroll
      for (int pt = 0; pt < 4; ++pt){
        int p = pt*16 + c16;
        xf[pt] = *reinterpret_cast<const short8*>(&xl[(p*256 + kc*32 + 8*g) ^ ((p&15)<<3)]);
      }
      #pragma unroll
      for (int oi = 0; oi < 2; ++oi){
        const int os = (half*2 + oi)*64 + osw;
        short8 wf = *reinterpret_cast<const short8*>(wqh_t + (size_t)kc*24576 + (512 + os + c16)*32 + 8*g);
        #pragma unroll
        for (int pt = 0; pt < 4; ++pt)
          acc[oi][pt] = MFMA(wf, xf[pt], acc[oi][pt], 0, 0, 0);
      }
    }
    #pragma unroll
    for (int oi = 0; oi < 2; ++oi){
      #pragma unroll
      for (int r = 0; r < 4; ++r){
        int c = (half*2 + oi)*64 + osw + 4*g + r;
        const float bias = b_qkv[512 + c];
        int hh = c >> 5, ch = c & 31;
        unsigned short* dst = v_t + (rb + hh*49)*2048 + ch*32;
        #pragma unroll
        for (int pt = 0; pt < 4; ++pt){
          int tok = pt*16 + c16;
          dst[(tok>>5)*1024 + (tok&31)] = f2bf(acc[oi][pt][r] + bias);
        }
      }
    }
  }
}

// ---------------- attention + fused LEPE per (n, head, region) ----------------
// Two-half ONLINE softmax with per-query oacc rescale (R20).
__global__ __launch_bounds__(256, 4) void k_attn(const unsigned short* __restrict__ q_rm,
                                                 const unsigned short* __restrict__ k_rm,
                                                 const unsigned short* __restrict__ v_t,
                                                 const int* __restrict__ idx,
                                                 const float* __restrict__ w_lepe,
                                                 const float* __restrict__ b_lepe,
                                                 unsigned short* __restrict__ att_hi,
                                                 unsigned short* __restrict__ att_lo){
  __shared__ unsigned short halo[10*320];   // [dy][c][10] (x+1), bank-step 5 over c
  __shared__ float wl_s[288];
  __shared__ float bl_s[32];

  // XCD-aware remap
  const int lin = blockIdx.x + 49*(blockIdx.y + 8*blockIdx.z);
  const int xcd = lin & 7, j = lin >> 3;
  const int jq = j / 49;
  const int qreg = j - jq*49;
  const int hn = jq*8 + xcd;
  const int h = hn & 7, n = hn >> 3;

  const int t = threadIdx.x, w = t>>6, g = (t>>4)&3, c16 = t&15;
  const int ry = qreg/7, rx = qreg%7;
  const int gy0 = ry*8;

  int4 ridx = *reinterpret_cast<const int4*>(idx + ((size_t)n*49 + qreg)*4);
  int regs[4] = {ridx.x, ridx.y, ridx.z, ridx.w};

  const size_t hb = ((size_t)(n*8 + h))*49;

  // ---- stage LEPE weights + materialized halo rows ----
  wl_s[t < 288 ? t : 0] = w_lepe[h*288 + (t < 288 ? t : 0)];
  if (t < 32){
    wl_s[256 + t] = w_lepe[h*288 + 256 + t];
    bl_s[t] = b_lepe[h*32 + t];
  }
  #pragma unroll
  for (int pass = 0; pass < 2; ++pass){
    int s = pass ? (256 + t) : t;
    if (pass == 0 || t < 64){
      const int dy = s >> 5, c = s & 31;
      const int yy = gy0 + dy - 1;
      short8 inner = {0,0,0,0,0,0,0,0};
      unsigned short eL = 0, eR = 0;
      if (yy >= 0 && yy < 56){
        const int iry = yy >> 3, y7 = yy & 7;
        const size_t rowb = (size_t)(y7>>2)*1024 + c*32 + (y7&3)*8;
        inner = *reinterpret_cast<const short8*>(v_t + (hb + iry*7 + rx)*2048 + rowb);
        if (rx > 0) eL = v_t[(hb + iry*7 + rx - 1)*2048 + rowb + 7];
        if (rx < 6) eR = v_t[(hb + iry*7 + rx + 1)*2048 + rowb];
      }
      unsigned short* drow = &halo[dy*320 + c*10];
      drow[0] = eL;
      #pragma unroll
      for (int jj2 = 0; jj2 < 8; ++jj2) drow[1 + jj2] = (unsigned short)inner[jj2];
      drow[9] = eR;
    }
  }

  // ---- Q frag (B operand) ----
  const int qtok = w*16 + c16;
  short8 qf = *reinterpret_cast<const short8*>(q_rm + (hb + qreg)*2048 + qtok*32 + 8*g);

  const float scale2 = 0.1767766952966369f * 1.4426950408889634f;
  const int srcA = (t & 15) | ((t & 16) << 1);
  const int srcB = srcA + 16;
  const bool gsel = (t & 32) != 0;

  float m_run = -3.4e38f, su = 0.f;
  f32x4 oacc[2] = {};

  #pragma unroll
  for (int h2 = 0; h2 < 2; ++h2){
    f32x4 s[8];
    #pragma unroll
    for (int f = 0; f < 8; ++f){
      const int tt = (f&3)*16 + c16;
      short8 kf = *reinterpret_cast<const short8*>(
          k_rm + (hb + regs[h2*2 + (f>>2)])*2048 + tt*32 + 8*g);
      f32x4 z = {0.f, 0.f, 0.f, 0.f};
      s[f] = MFMA(kf, qf, z, 0, 0, 0);
    }

    float ml = -3.4e38f;
    #pragma unroll
    for (int f = 0; f < 8; ++f)
      #pragma unroll
      for (int r = 0; r < 4; ++r) ml = fmaxf(ml, s[f][r]);
    ml = fmaxf(ml, __shfl_xor(ml, 16, 64));
    ml = fmaxf(ml, __shfl_xor(ml, 32, 64));

    const float mnew = (h2 == 0) ? ml : fmaxf(m_run, ml);
    if (h2 != 0){
      const float resc = exp2f((m_run - mnew) * scale2);
      su *= resc;
      float rq[4];
      #pragma unroll
      for (int r = 0; r < 4; ++r)
        rq[r] = __shfl(resc, 4*g + r, 64);
      #pragma unroll
      for (int dt = 0; dt < 2; ++dt)
        #pragma unroll
        for (int r = 0; r < 4; ++r)
          oacc[dt][r] *= rq[r];
    }
    m_run = mnew;

    const float nms = -mnew * scale2;
    #pragma unroll
    for (int f = 0; f < 8; ++f)
      #pragma unroll
      for (int r = 0; r < 4; ++r){
        float e = exp2f(fmaf(s[f][r], scale2, nms));
        s[f][r] = e; su += e;
      }

    #pragma unroll
    for (int tcl = 0; tcl < 4; ++tcl){
      const int fb = (tcl>>1)*4 + (tcl&1)*2;
      unsigned int a0 = cvtpk(s[fb][0],   s[fb][1]);
      unsigned int a1 = cvtpk(s[fb][2],   s[fb][3]);
      unsigned int b0 = cvtpk(s[fb+1][0], s[fb+1][1]);
      unsigned int b1 = cvtpk(s[fb+1][2], s[fb+1][3]);
      unsigned int wa0 = __shfl((int)a0, srcA, 64), wa1 = __shfl((int)a1, srcA, 64);
      unsigned int wa2 = __shfl((int)a0, srcB, 64), wa3 = __shfl((int)a1, srcB, 64);
      unsigned int wb0 = __shfl((int)b0, srcA, 64), wb1 = __shfl((int)b1, srcA, 64);
      unsigned int wb2 = __shfl((int)b0, srcB, 64), wb3 = __shfl((int)b1, srcB, 64);
      union { unsigned int u[4]; short8 s8; } pfu;
      pfu.u[0] = gsel ? wb0 : wa0;
      pfu.u[1] = gsel ? wb1 : wa1;
      pfu.u[2] = gsel ? wb2 : wa2;
      pfu.u[3] = gsel ? wb3 : wa3;
      const size_t vb = (hb + regs[h2*2 + (tcl>>1)])*2048 + (tcl&1)*1024 + 8*g;
      #pragma unroll
      for (int dt = 0; dt < 2; ++dt){
        short8 vf = *reinterpret_cast<const short8*>(v_t + vb + (dt*16 + c16)*32);
        oacc[dt] = MFMA(pfu.s8, vf, oacc[dt], 0, 0, 0);
      }
    }
  }

  su += __shfl_xor(su, 16, 64);
  su += __shfl_xor(su, 32, 64);
  const float inv_lane = __builtin_amdgcn_rcpf(su);
  float invq[4];
  #pragma unroll
  for (int r = 0; r < 4; ++r)
    invq[r] = __shfl(inv_lane, 4*g + r, 64);

  __syncthreads();
  const int tok0 = w*16 + 4*g;
  const int ty = tok0>>3, tx0 = tok0&7;
  #pragma unroll
  for (int dt = 0; dt < 2; ++dt){
    const int cl = dt*16 + c16;
    float wl[9];
    #pragma unroll
    for (int kk = 0; kk < 9; ++kk) wl[kk] = wl_s[cl*9 + kk];
    const float bl = bl_s[cl];
    float vwin[3][6];
    #pragma unroll
    for (int dy = 0; dy < 3; ++dy){
      const unsigned short* hrow = &halo[(ty+dy)*320 + cl*10 + tx0];
      #pragma unroll
      for (int jj = 0; jj < 6; ++jj)
        vwin[dy][jj] = bf2f(hrow[jj]);
    }
    #pragma unroll
    for (int r = 0; r < 4; ++r){
      float a = fmaf(oacc[dt][r], invq[r], bl);
      #pragma unroll
      for (int dy = 0; dy < 3; ++dy)
        #pragma unroll
        for (int dx = 0; dx < 3; ++dx)
          a += wl[dy*3 + dx] * vwin[dy][r + dx];
      int tok = tok0 + r;
      size_t o = ((size_t)(n*49 + qreg)*8 + h)*2048 + tok*32 + dt*16 + c16;
      unsigned short hi = (unsigned short)cvtpk(a, a);
      att_hi[o] = hi;
      float alo = a - bf2f(hi);
      att_lo[o] = (unsigned short)cvtpk(alo, alo);
    }
  }
}

// ---------------- output projection (R14 exact: bf16x3; ah/al 16B loads; XCD write-merge) ----------------
__global__ __launch_bounds__(512) void k_oproj(const unsigned short* __restrict__ ah_,
                                               const unsigned short* __restrict__ al_,
                                               const unsigned short* __restrict__ wh_t,
                                               const unsigned short* __restrict__ wl_t,
                                               const float* __restrict__ b_out,
                                               float* __restrict__ out){
  const int lin = blockIdx.x;
  const int jobid = (lin & 7)*98 + (lin >> 3);
  const int reg = jobid % 49, n = jobid / 49;
  const int t = threadIdx.x, w8 = t>>6, g = (t>>4)&3, c16 = t&15;
  const int ry = reg/7, rx = reg%7;
  const size_t abase = ((size_t)(n*49 + reg))*8*2048;
  const int os1 = w8*16, os2 = os1 + 128;
  f32x4 acc[2][4] = {};
  for (int kc = 0; kc < 8; ++kc){
    const size_t wb = (size_t)kc*8192 + 8*g;
    short8 wh1 = *reinterpret_cast<const short8*>(wh_t + wb + (os1 + c16)*32);
    short8 wl1 = *reinterpret_cast<const short8*>(wl_t + wb + (os1 + c16)*32);
    short8 wh2 = *reinterpret_cast<const short8*>(wh_t + wb + (os2 + c16)*32);
    short8 wl2 = *reinterpret_cast<const short8*>(wl_t + wb + (os2 + c16)*32);
    #pragma unroll
    for (int pt = 0; pt < 4; ++pt){
      size_t off = abase + (size_t)kc*2048 + (pt*16 + c16)*32 + 8*g;
      short8 xh = *reinterpret_cast<const short8*>(ah_ + off);
      short8 xl = *reinterpret_cast<const short8*>(al_ + off);
      acc[0][pt] = MFMA(wh1, xh, acc[0][pt], 0, 0, 0);
      acc[0][pt] = MFMA(wh1, xl, acc[0][pt], 0, 0, 0);
      acc[0][pt] = MFMA(wl1, xh, acc[0][pt], 0, 0, 0);
      acc[1][pt] = MFMA(wh2, xh, acc[1][pt], 0, 0, 0);
      acc[1][pt] = MFMA(wh2, xl, acc[1][pt], 0, 0, 0);
      acc[1][pt] = MFMA(wl2, xh, acc[1][pt], 0, 0, 0);
    }
  }
  #pragma unroll
  for (int s = 0; s < 2; ++s){
    const int os = s ? os2 : os1;
    #pragma unroll
    for (int r = 0; r < 4; ++r){
      int o = os + 4*g + r;
      float bias = b_out[o];
      #pragma unroll
      for (int pt = 0; pt < 4; ++pt){
        int tok = pt*16 + c16;
        int p = (ry*8 + (tok>>3))*56 + rx*8 + (tok&7);
        out[((size_t)n*256 + o)*3136 + p] = acc[s][pt][r] + bias;
      }
    }
  }
}

extern "C" void kernel_launch(void* const* d_in, const int* in_sizes, int n_in,
                              void* d_out, int out_size, void* d_ws, size_t ws_size,
                              hipStream_t stream){
  const float* x      = (const float*)d_in[0];
  const float* w_qkv  = (const float*)d_in[1];
  const float* b_qkv  = (const float*)d_in[2];
  const float* w_lepe = (const float*)d_in[3];
  const float* b_lepe = (const float*)d_in[4];
  const float* w_out  = (const float*)d_in[5];
  const float* b_out  = (const float*)d_in[6];
  float* out = (float*)d_out;

  char* ws = (char*)d_ws;
  size_t off = 0;
  auto take = [&](size_t bytes)->char*{
    char* p = ws + off; off += (bytes + 255) & ~(size_t)255; return p;
  };
  const size_t TEN = (size_t)16*3136*256*2; // bf16 full tensor
  unsigned short* q_rm   = (unsigned short*)take(TEN);
  unsigned short* k_rm   = (unsigned short*)take(TEN);
  unsigned short* v_t    = (unsigned short*)take(TEN);
  unsigned short* att_hi = (unsigned short*)take(TEN);
  unsigned short* att_lo = (unsigned short*)take(TEN);
  float* xbar = (float*)take((size_t)16*49*256*4);
  float* q_r  = (float*)take((size_t)16*49*256*4);
  float* k_r  = (float*)take((size_t)16*49*256*4);
  int*   idxb = (int*)take((size_t)16*49*4*4);
  unsigned short* wqh_t = (unsigned short*)take((size_t)768*256*2);
  unsigned short* woh_t = (unsigned short*)take((size_t)256*256*2);
  unsigned short* wol_t = (unsigned short*)take((size_t)256*256*2);

  k_prep <<<dim3(1024), 256, 0, stream>>>(w_qkv, w_out, wqh_t, woh_t, wol_t);
  k_qkv  <<<dim3(4704), 256, 0, stream>>>(x, wqh_t, b_qkv, q_rm, k_rm, v_t, xbar);
  k_qrkr <<<dim3(8, 16, 7), 256, 0, stream>>>(xbar, w_qkv, b_qkv, q_r, k_r);
  k_topk <<<dim3(49, 16), 64, 0, stream>>>(q_r, k_r, idxb);
  k_attn <<<dim3(49, 8, 16), 256, 0, stream>>>(q_rm, k_rm, v_t, idxb, w_lepe, b_lepe, att_hi, att_lo);
  k_oproj<<<dim3(784), 512, 0, stream>>>(att_hi, att_lo, woh_t, wol_t, b_out, out);
}